// Round 8
// baseline (370.116 us; speedup 1.0000x reference)
//
#include <hip/hip_runtime.h>
#include <hip/hip_bf16.h>
#include <math.h>

// Problem dims (fixed by reference)
#define BATCH   2
#define SEQ     2048
#define D_MODEL 1024
#define NHEAD   16
#define HEADD   64
#define NROWS   (BATCH * SEQ)   // 4096
#define D_FF    4096
#define TPARTS  4               // attention t-split factor
#define TSPAN   (SEQ / TPARTS)  // 512

typedef __bf16 bf16_t;
typedef __bf16 bf16x2 __attribute__((ext_vector_type(2)));
typedef __bf16 bf16x4 __attribute__((ext_vector_type(4)));
typedef __bf16 bf16x8 __attribute__((ext_vector_type(8)));
typedef float  f32x4  __attribute__((ext_vector_type(4)));

#define QSCALE 0.18033688011112042f   // 0.125 * log2(e), folded into Q

// async global->LDS, 16B per lane, dest = wave-uniform base + lane*16
__device__ __forceinline__ void gload_lds16(const void* g, void* l) {
    __builtin_amdgcn_global_load_lds(
        (const __attribute__((address_space(1))) unsigned int*)g,
        (__attribute__((address_space(3))) unsigned int*)l, 16, 0, 0);
}

// ---------------------------------------------------------------------------
// Fused weight transpose + fp32 -> bf16 for all six weights (one launch).
// ---------------------------------------------------------------------------
__global__ __launch_bounds__(256) void transpose_all6(
    const float* __restrict__ Wq, const float* __restrict__ Wk,
    const float* __restrict__ Wv, const float* __restrict__ Wp,
    const float* __restrict__ W1, const float* __restrict__ W2,
    bf16_t* __restrict__ Wqkvt, bf16_t* __restrict__ Wpt,
    bf16_t* __restrict__ W1t, bf16_t* __restrict__ W2t)
{
    __shared__ float tile[32][33];
    int bid = blockIdx.x;
    const float* W; bf16_t* Wt; int K, N, n0, k0;
    if (bid < 4096) {
        int seg = bid >> 10, t = bid & 1023;
        W  = (seg == 0) ? Wq : (seg == 1) ? Wk : (seg == 2) ? Wv : Wp;
        Wt = (seg < 3) ? (Wqkvt + (size_t)seg * 1024 * 1024) : Wpt;
        K = 1024; N = 1024;
        n0 = (t & 31) * 32; k0 = (t >> 5) * 32;
    } else if (bid < 8192) {
        int t = bid - 4096;
        W = W1; Wt = W1t; K = 1024; N = 4096;
        n0 = (t & 127) * 32; k0 = (t >> 7) * 32;
    } else {
        int t = bid - 8192;
        W = W2; Wt = W2t; K = 4096; N = 1024;
        n0 = (t & 31) * 32; k0 = (t >> 5) * 32;
    }
    int tx = threadIdx.x;   // 0..31
    int ty = threadIdx.y;   // 0..7
    #pragma unroll
    for (int i = 0; i < 32; i += 8)
        tile[ty + i][tx] = W[(size_t)(k0 + ty + i) * N + n0 + tx];
    __syncthreads();
    #pragma unroll
    for (int i = 0; i < 32; i += 8)
        Wt[(size_t)(n0 + ty + i) * K + k0 + tx] = (bf16_t)tile[tx][ty + i];
}

// ---------------------------------------------------------------------------
// LayerNorm: fp32 [rows][1024] -> bf16 [rows][1024].  One block per row.
// ---------------------------------------------------------------------------
__global__ __launch_bounds__(256) void ln_kernel(
    const float* __restrict__ x, const float* __restrict__ g,
    const float* __restrict__ b, bf16_t* __restrict__ out)
{
    int row = blockIdx.x;
    int tid = threadIdx.x;
    const float* xr = x + (size_t)row * D_MODEL;
    f32x4 v = *(const f32x4*)(xr + tid * 4);
    float s  = v[0] + v[1] + v[2] + v[3];
    float s2 = v[0]*v[0] + v[1]*v[1] + v[2]*v[2] + v[3]*v[3];
    #pragma unroll
    for (int off = 32; off; off >>= 1) {
        s  += __shfl_down(s, off);
        s2 += __shfl_down(s2, off);
    }
    __shared__ float ps[4], ps2[4];
    int w = tid >> 6, lane = tid & 63;
    if (lane == 0) { ps[w] = s; ps2[w] = s2; }
    __syncthreads();
    float sum  = ps[0] + ps[1] + ps[2] + ps[3];
    float sum2 = ps2[0] + ps2[1] + ps2[2] + ps2[3];
    float mu  = sum * (1.0f / D_MODEL);
    float var = sum2 * (1.0f / D_MODEL) - mu * mu;
    float rs  = rsqrtf(var + 1e-5f);
    #pragma unroll
    for (int j = 0; j < 4; ++j) {
        int c = tid * 4 + j;
        out[(size_t)row * D_MODEL + c] = (bf16_t)((v[j] - mu) * rs * g[c] + b[c]);
    }
}

// ---------------------------------------------------------------------------
// 256x256 GEMM, 8-wave COUNTED-vmcnt C-quadrant schedule (R17):
// R7's port (vmcnt(0) at K-tile top) is the drain-0 anti-pattern (m218:
// counted-vs-drain0 = +38-73%).  Restructured so counted waits are legal:
// phases iterate C-quadrants (ah,bh) = (0,0),(0,1),(1,0),(1,1); staging is
// 8 need-ordered ROUNDS of 64 rows (1 gload/wave each, LDS round-blocked,
// DMA-linear, chunk-XOR swizzle rule #21):
//   A0_0,A0_1 (A first halves, needed q0) ; B0_0,B0_1 (B bh=0, q0) ;
//   B1_0,B1_1 (B bh=1, q1) ; A1_0,A1_1 (A second halves, q2).
// Issue slots during iter t (AFTER each phase barrier, into buf^1 -- the q0
// barrier post-dates all t-1 reads of buf^1 via each wave's q3 lgkmcnt(0)):
//   q0: A0 pair, q1: B0 pair, q2: B1 pair, q3: A1 pair.
// FIFO vmcnt waits (m135): steady {4,4,4,6}, last iter {4,2,0,0} -- every
// load gets >=3 phases (~450-750cy) of in-flight cover; never drain-0.
// Barrier-per-phase publishes cross-wave round pieces.  T5 setprio around
// the 16-MFMA cluster.  Per-wave C = 128x64: acc[8][4].
// EPI 2: + bias -> GELU -> bf16.   EPI 6: fused QKV scatter epilogue.
// ---------------------------------------------------------------------------
template<int EPI>
__global__ __launch_bounds__(512) void gemm256(
    const bf16_t* __restrict__ A, const bf16_t* __restrict__ Bt,
    const float* __restrict__ bias, void* __restrict__ out,
    int M, int N, int K)
{
    __shared__ bf16_t As[2][4][4096];   // [buf][round][64 rows x 64 k]
    __shared__ bf16_t Bs[2][4][4096];
    int tid = threadIdx.x;               // 0..511
    int bid = blockIdx.x;
    int m0 = (bid & 15) * 256;           // GX = M/256 = 16
    int n0 = (bid >> 4) * 256;
    int w = tid >> 6, lane = tid & 63, quad = lane >> 4, l15 = lane & 15;
    int g = w >> 2;                      // A row-group (0/1)
    int wm = g * 128, wn = (w & 3) * 64;
    int rxs = l15 & 7;

    // staging: srow = LDS within-round row (0..63); chunk slot tid&7
    int srow = tid >> 3;
    int sx = (((tid & 7) ^ (srow & 7)) << 3);   // inverse-swz source chunk

    // per-round global source rows:
    //   A round r: row = (r&1)*128 + (r>>1)*64 + srow
    //   B round r: row = ((r&1)*2 + (srow>>5))*64 + (r>>1)*32 + (srow&31)
    const bf16_t* Asrc[4]; const bf16_t* Bsrc[4];
    #pragma unroll
    for (int r = 0; r < 4; ++r) {
        int ra = (r & 1) * 128 + (r >> 1) * 64 + srow;
        int rb = ((r & 1) * 2 + (srow >> 5)) * 64 + (r >> 1) * 32 + (srow & 31);
        Asrc[r] = A  + (size_t)(m0 + ra) * K + sx;
        Bsrc[r] = Bt + (size_t)(n0 + rb) * K + sx;
    }

    f32x4 acc[8][4] = {};
    int nt = K >> 6;

    // prologue: tile 0 -> buf 0, in need order
    gload_lds16(Asrc[0], &As[0][0][w * 512]);
    gload_lds16(Asrc[1], &As[0][1][w * 512]);
    gload_lds16(Bsrc[0], &Bs[0][0][w * 512]);
    gload_lds16(Bsrc[1], &Bs[0][1][w * 512]);
    gload_lds16(Bsrc[2], &Bs[0][2][w * 512]);
    gload_lds16(Bsrc[3], &Bs[0][3][w * 512]);
    gload_lds16(Asrc[2], &As[0][2][w * 512]);
    gload_lds16(Asrc[3], &As[0][3][w * 512]);

    for (int t = 0; t < nt; ++t) {
        int cur = t & 1, nb = cur ^ 1;
        bool pf = (t + 1 < nt);
        int k1 = (t + 1) << 6;
        bf16x8 af[4][2];
        #pragma unroll
        for (int q = 0; q < 4; ++q) {
            constexpr int dummy = 0; (void)dummy;
            int ah = q >> 1, bh = q & 1;
            // counted waits: steady {4,4,4,6}; last iter {4,2,0,0}
            if (q == 0) {
                asm volatile("s_waitcnt vmcnt(4)" ::: "memory");
            } else if (pf) {
                if (q == 3) asm volatile("s_waitcnt vmcnt(6)" ::: "memory");
                else        asm volatile("s_waitcnt vmcnt(4)" ::: "memory");
            } else {
                if (q == 1) asm volatile("s_waitcnt vmcnt(2)" ::: "memory");
                else        asm volatile("s_waitcnt vmcnt(0)" ::: "memory");
            }
            __builtin_amdgcn_s_barrier();      // publish rounds across waves
            __builtin_amdgcn_sched_barrier(0);
            if (pf) {                          // issue next tile's slot (buf^1)
                if (q == 0) {
                    gload_lds16(Asrc[0] + k1, &As[nb][0][w * 512]);
                    gload_lds16(Asrc[1] + k1, &As[nb][1][w * 512]);
                } else if (q == 1) {
                    gload_lds16(Bsrc[0] + k1, &Bs[nb][0][w * 512]);
                    gload_lds16(Bsrc[1] + k1, &Bs[nb][1][w * 512]);
                } else if (q == 2) {
                    gload_lds16(Bsrc[2] + k1, &Bs[nb][2][w * 512]);
                    gload_lds16(Bsrc[3] + k1, &Bs[nb][3][w * 512]);
                } else {
                    gload_lds16(Asrc[2] + k1, &As[nb][2][w * 512]);
                    gload_lds16(Asrc[3] + k1, &As[nb][3][w * 512]);
                }
            }
            if ((q & 1) == 0) {                // A half ah -> registers
                #pragma unroll
                for (int ii = 0; ii < 4; ++ii)
                    #pragma unroll
                    for (int kk = 0; kk < 2; ++kk)
                        af[ii][kk] = *(const bf16x8*)&As[cur][ah * 2 + g]
                            [(ii * 16 + l15) * 64 + ((((kk << 2) | quad) ^ rxs) << 3)];
            }
            bf16x8 bfr[2][2];
            #pragma unroll
            for (int jj = 0; jj < 2; ++jj)
                #pragma unroll
                for (int kk = 0; kk < 2; ++kk)
                    bfr[jj][kk] = *(const bf16x8*)&Bs[cur][bh * 2 + ((w >> 1) & 1)]
                        [((w & 1) * 32 + jj * 16 + l15) * 64 + ((((kk << 2) | quad) ^ rxs) << 3)];
            asm volatile("s_waitcnt lgkmcnt(0)" ::: "memory");
            __builtin_amdgcn_sched_barrier(0);
            __builtin_amdgcn_s_setprio(1);
            #pragma unroll
            for (int ii = 0; ii < 4; ++ii)
                #pragma unroll
                for (int jj = 0; jj < 2; ++jj)
                    #pragma unroll
                    for (int kk = 0; kk < 2; ++kk)
                        acc[4 * ah + ii][2 * bh + jj] = __builtin_amdgcn_mfma_f32_16x16x32_bf16(
                            af[ii][kk], bfr[jj][kk], acc[4 * ah + ii][2 * bh + jj], 0, 0, 0);
            __builtin_amdgcn_s_setprio(0);
            __builtin_amdgcn_sched_barrier(0);
        }
    }

    #pragma unroll
    for (int i = 0; i < 8; ++i)
    #pragma unroll
    for (int j = 0; j < 4; ++j) {
        int col  = n0 + wn + j * 16 + l15;
        int row0 = m0 + wm + i * 16 + quad * 4;
        if (EPI == 6) {
            int region = (n0 + wn + j * 16) >> 10;   // 0=Q 1=K 2=V (uniform per j-tile)
            if (region < 2) {
                #pragma unroll
                for (int r = 0; r < 4; ++r) {
                    int row = row0 + r;
                    float v = acc[i][j][r];
                    if (region == 0) v *= QSCALE;
                    int b = row >> 11, s = row & 2047, hh = (col & 1023) >> 6, d = col & 63;
                    bf16_t* dst = (bf16_t*)out + (size_t)region * 4194304;
                    dst[(((size_t)(b * NHEAD + hh)) * SEQ + s) * HEADD + d] = (bf16_t)v;
                }
            } else {
                int dg = col - 2048, hh = dg >> 6, d = dg & 63;
                int b = row0 >> 11, s0 = row0 & 2047;
                bf16x4 pv;
                #pragma unroll
                for (int r = 0; r < 4; ++r) pv[r] = (bf16_t)acc[i][j][r];
                *(bf16x4*)((bf16_t*)out + 8388608
                           + (((size_t)(b * NHEAD + hh)) * HEADD + d) * SEQ + s0) = pv;
            }
        } else {
            float bv = bias[col];
            #pragma unroll
            for (int r = 0; r < 4; ++r) {
                int row = row0 + r;
                float u = acc[i][j][r] + bv;
                float y = u * (0.7978845608028654f + 0.03567740814f * u * u);
                float e = __builtin_amdgcn_exp2f(2.8853900817779268f * y);
                float r8 = __builtin_amdgcn_rcpf(e + 1.0f);
                ((bf16_t*)out)[(size_t)row * N + col] = (bf16_t)(u - u * r8);
            }
        }
    }
}

// ---------------------------------------------------------------------------
// 128xBN GEMM, BK=64, counted-vmcnt pipeline (R4/R6-proven config).
// EPI 1: + bias + bf16 residual -> fp32 out;  EPI 3: + bias + fp32 residual
// -> fp32 out.
// ---------------------------------------------------------------------------
template<int EPI, int BN>
__global__ __launch_bounds__(256) void gemm128(
    const bf16_t* __restrict__ A, const bf16_t* __restrict__ Bt,
    const float* __restrict__ bias, const void* __restrict__ resid,
    void* __restrict__ out, int M, int N, int K, int RY)
{
    constexpr int JN = BN / 32;           // j-tiles per wave
    constexpr int NBUF = (BN == 64) ? 3 : 2;
    __shared__ bf16_t As[NBUF][128 * 64];   // [buf][row][k], swizzled chunks
    __shared__ bf16_t Bs[NBUF][BN * 64];
    int tid = threadIdx.x;
    // XCD supertile swizzle (bijective; grid is 1D, GX=32)
    int bid = blockIdx.x;
    int cx = bid & 3, cy = (bid >> 2) & 1, i0 = bid >> 3;
    int m0 = ((cx << 3) + (i0 & 7)) << 7;       // x * 128
    int n0 = (cy * RY + (i0 >> 3)) * BN;
    int w = tid >> 6, lane = tid & 63, quad = lane >> 4, l15 = lane & 15;
    int wm = (w & 1) * 64, wn = (w >> 1) * (BN / 2);
    int srow = tid >> 3;              // 0..31 (staging row within pass)
    int sxor = (((tid & 7) ^ (srow & 7)) << 3);

    const bf16_t* Ap = A  + (size_t)(m0 + srow) * K + sxor;
    const bf16_t* Bp = Bt + (size_t)(n0 + srow) * K + sxor;

    int rxs = l15 & 7;                // read-side xor (chunk units); row&7==l15&7

    auto stage = [&](int buf, int k0) {
        bf16_t* AsW = &As[buf][w * 512];   // wave-uniform dest (8 rows * 64)
        bf16_t* BsW = &Bs[buf][w * 512];
        #pragma unroll
        for (int p = 0; p < 4; ++p)
            gload_lds16(Ap + (size_t)p * 32 * K + k0, AsW + p * 2048);
        #pragma unroll
        for (int p = 0; p < JN; ++p)
            gload_lds16(Bp + (size_t)p * 32 * K + k0, BsW + p * 2048);
    };

    f32x4 acc[4][JN] = {};

    int nt = K >> 6;
    stage(0, 0);                           // prologue: tile 0 -> buf 0
    if (NBUF == 3 && nt > 1) stage(1, 64); // depth-2 prologue: tile 1 -> buf 1
    for (int t = 0; t < nt; ++t) {
        int cur = t % NBUF;
        if constexpr (NBUF == 3) {
            if (t + 2 < nt) {
                stage((t + 2) % NBUF, (t + 2) << 6);
                asm volatile("s_waitcnt vmcnt(12)" ::: "memory");
            } else if (t + 1 < nt) {
                asm volatile("s_waitcnt vmcnt(6)" ::: "memory");
            } else {
                asm volatile("s_waitcnt vmcnt(0)" ::: "memory");
            }
        } else {
            if (t + 1 < nt) {
                stage((t + 1) % NBUF, (t + 1) << 6);
                asm volatile("s_waitcnt vmcnt(8)" ::: "memory");
            } else {
                asm volatile("s_waitcnt vmcnt(0)" ::: "memory");
            }
        }
        __builtin_amdgcn_s_barrier();      // current tile fully in LDS
        __builtin_amdgcn_sched_barrier(0);
        #pragma unroll
        for (int kk = 0; kk < 2; ++kk) {
            bf16x8 af[4], bfr[JN];
            #pragma unroll
            for (int i = 0; i < 4; ++i)
                af[i] = *(const bf16x8*)&As[cur][(wm + i * 16 + l15) * 64
                                            + ((((kk << 2) | quad) ^ rxs) << 3)];
            #pragma unroll
            for (int j = 0; j < JN; ++j)
                bfr[j] = *(const bf16x8*)&Bs[cur][(wn + j * 16 + l15) * 64
                                            + ((((kk << 2) | quad) ^ rxs) << 3)];
            #pragma unroll
            for (int i = 0; i < 4; ++i)
                #pragma unroll
                for (int j = 0; j < JN; ++j)
                    acc[i][j] = __builtin_amdgcn_mfma_f32_16x16x32_bf16(af[i], bfr[j], acc[i][j], 0, 0, 0);
        }
        __builtin_amdgcn_sched_barrier(0);
        asm volatile("s_waitcnt lgkmcnt(0)" ::: "memory");  // my reads done
        __builtin_amdgcn_s_barrier();      // all readers done -> buf reusable
        __builtin_amdgcn_sched_barrier(0);
    }

    #pragma unroll
    for (int i = 0; i < 4; ++i)
    #pragma unroll
    for (int j = 0; j < JN; ++j) {
        int col  = n0 + wn + j * 16 + l15;
        int row0 = m0 + wm + i * 16 + quad * 4;
        float bv = bias[col];
        #pragma unroll
        for (int r = 0; r < 4; ++r) {
            int row = row0 + r;
            float vacc = acc[i][j][r] + bv;
            if (EPI == 1) {
                float res = (float)((const bf16_t*)resid)[(size_t)row * N + col];
                ((float*)out)[(size_t)row * N + col] = vacc + res;
            } else {
                float res = ((const float*)resid)[(size_t)row * N + col];
                ((float*)out)[(size_t)row * N + col] = vacc + res;
            }
        }
    }
}

// ---------------------------------------------------------------------------
// Attention partial kernel.  No-max softmax (Q pre-scaled; exp2 direct) is
// LINEAR in t -> TPARTS=4 t-ranges of 512; partial o (bf16) + partial l.
// ---------------------------------------------------------------------------
__global__ __launch_bounds__(256, 4) void attn_kernel(
    const bf16_t* __restrict__ q, const bf16_t* __restrict__ k,
    const bf16_t* __restrict__ vt, bf16_t* __restrict__ po,
    float* __restrict__ plsum)
{
    int gid = blockIdx.x;                 // 0..2047
    int xcd = gid & 7;                    // presumed XCD (any bijection safe)
    int loc = gid >> 3;                   // 0..255
    int bh  = xcd * 4 + (loc >> 6);       // 4 consecutive heads per XCD
    int rest = loc & 63;
    int qt   = rest >> 2;                 // q-tile 0..15
    int part = rest & 3;                  // t-part 0..3
    int tb0 = part * TSPAN, tend = tb0 + TSPAN;
    int b = bh >> 4, h = bh & 15;
    int tid = threadIdx.x, w = tid >> 6, lane = tid & 63;
    int quad = lane >> 4, l15 = lane & 15;
    int qbase = qt * 128 + w * 32;
    const bf16_t* qh = q  + (size_t)bh * SEQ * HEADD;
    const bf16_t* kh = k  + (size_t)bh * SEQ * HEADD;
    const bf16_t* vh = vt + (size_t)bh * HEADD * SEQ;   // [d][t]

    bf16x8 qa[2][2];
    #pragma unroll
    for (int m = 0; m < 2; ++m)
        #pragma unroll
        for (int hf = 0; hf < 2; ++hf)
            qa[m][hf] = *(const bf16x8*)(qh + (size_t)(qbase + m * 16 + l15) * HEADD + hf * 32 + quad * 8);

    bf16x8 ones;
    #pragma unroll
    for (int j = 0; j < 8; ++j) ones[j] = (bf16_t)1.0f;

    __shared__ alignas(16) bf16_t Ks[32 * 72];     // [t][d], rows padded to 72
    __shared__ alignas(16) bf16_t Vs[64 * 40];     // [d][t], rows padded to 40
    __shared__ alignas(16) bf16_t Pl[4][32][40];   // per-wave P (32q x 32t)

    // staging indices: K tile is 4KB contiguous; V tile is 64 rows x 64B
    int ksrow = tid >> 3, kscol = (tid & 7) * 8;   // t-row, d-chunk
    int vsrow = tid >> 2, vscol = (tid & 3) * 8;   // d-row, t-chunk
    const bf16_t* kg = kh + (size_t)ksrow * HEADD + kscol;
    const bf16_t* vg = vh + (size_t)vsrow * SEQ + vscol;

    f32x4 o[2][4] = {};
    f32x4 ls[2] = {};

    for (int t0 = tb0; t0 < tend; t0 += 32) {
        bf16x8 kreg = *(const bf16x8*)(kg + (size_t)t0 * HEADD);
        bf16x8 vreg = *(const bf16x8*)(vg + t0);
        __syncthreads();                           // prev-iter readers done
        *(bf16x8*)&Ks[ksrow * 72 + kscol] = kreg;
        *(bf16x8*)&Vs[vsrow * 40 + vscol] = vreg;
        __syncthreads();                           // tiles visible

        bf16x8 kb[2][2], vf[4];
        #pragma unroll
        for (int jt = 0; jt < 2; ++jt)
            #pragma unroll
            for (int hf = 0; hf < 2; ++hf)
                kb[jt][hf] = *(const bf16x8*)&Ks[(2 * l15 + jt) * 72 + hf * 32 + quad * 8];
        #pragma unroll
        for (int dn = 0; dn < 4; ++dn)
            vf[dn] = *(const bf16x8*)&Vs[(dn * 16 + l15) * 40 + quad * 8];

        #pragma unroll
        for (int m = 0; m < 2; ++m) {
            f32x4 sc[2];
            #pragma unroll
            for (int jt = 0; jt < 2; ++jt) {
                f32x4 z = {};
                z = __builtin_amdgcn_mfma_f32_16x16x32_bf16(qa[m][0], kb[jt][0], z, 0, 0, 0);
                z = __builtin_amdgcn_mfma_f32_16x16x32_bf16(qa[m][1], kb[jt][1], z, 0, 0, 0);
                sc[jt] = z;
            }
            int qm = qbase + m * 16;
            bool dg = (t0 < qm + 16) && (t0 + 32 > qm);  // wave-uniform
            #pragma unroll
            for (int r = 0; r < 4; ++r) {
                int qrow = qm + quad * 4 + r;
                float p0 = __builtin_amdgcn_exp2f(sc[0][r]);
                float p1 = __builtin_amdgcn_exp2f(sc[1][r]);
                if (dg) {
                    int tg = t0 + 2 * l15;
                    if (tg == qrow)     p0 = 0.0f;
                    if (tg + 1 == qrow) p1 = 0.0f;
                }
                bf16x2 pp = { (bf16_t)p0, (bf16_t)p1 };
                *(bf16x2*)&Pl[w][m * 16 + quad * 4 + r][2 * l15] = pp;
            }
        }
        #pragma unroll
        for (int m = 0; m < 2; ++m) {
            bf16x8 pf = *(const bf16x8*)&Pl[w][m * 16 + l15][quad * 8];
            ls[m] = __builtin_amdgcn_mfma_f32_16x16x32_bf16(pf, ones, ls[m], 0, 0, 0);
            #pragma unroll
            for (int dn = 0; dn < 4; ++dn)
                o[m][dn] = __builtin_amdgcn_mfma_f32_16x16x32_bf16(pf, vf[dn], o[m][dn], 0, 0, 0);
        }
    }

    // partial o (bf16, undivided) and partial l (fp32; every lane holds full sum)
    #pragma unroll
    for (int m = 0; m < 2; ++m)
        #pragma unroll
        for (int dn = 0; dn < 4; ++dn)
            #pragma unroll
            for (int r = 0; r < 4; ++r) {
                int qrow = qbase + m * 16 + quad * 4 + r;
                po[(((size_t)part * NROWS) + b * SEQ + qrow) * D_MODEL
                   + h * HEADD + dn * 16 + l15] = (bf16_t)o[m][dn][r];
            }
    if (l15 == 0) {
        #pragma unroll
        for (int m = 0; m < 2; ++m)
            #pragma unroll
            for (int r = 0; r < 4; ++r) {
                int qrow = qbase + m * 16 + quad * 4 + r;
                plsum[((size_t)part * 32 + bh) * SEQ + qrow] = ls[m][r];
            }
    }
}

// ---------------------------------------------------------------------------
// Merge attention partials: y = (sum_p o_p) / (sum_p l_p), bf16 out.
// ---------------------------------------------------------------------------
__global__ __launch_bounds__(256) void attn_merge(
    const bf16_t* __restrict__ po, const float* __restrict__ plsum,
    bf16_t* __restrict__ y)
{
    int row = blockIdx.x;
    int tid = threadIdx.x;
    int c = tid * 4;
    int b = row >> 11, s = row & 2047;
    int bh = b * NHEAD + (c >> 6);
    float l = 0.0f;
    f32x4 ov = {};
    #pragma unroll
    for (int p = 0; p < TPARTS; ++p) {
        l += plsum[((size_t)p * 32 + bh) * SEQ + s];
        bf16x4 t = *(const bf16x4*)&po[((size_t)p * NROWS + row) * D_MODEL + c];
        #pragma unroll
        for (int j = 0; j < 4; ++j) ov[j] += (float)t[j];
    }
    float rl = 1.0f / l;
    bf16x4 out;
    #pragma unroll
    for (int j = 0; j < 4; ++j) out[j] = (bf16_t)(ov[j] * rl);
    *(bf16x4*)&y[(size_t)row * D_MODEL + c] = out;
}

// ---------------------------------------------------------------------------
extern "C" void kernel_launch(void* const* d_in, const int* in_sizes, int n_in,
                              void* d_out, int out_size, void* d_ws, size_t ws_size,
                              hipStream_t stream)
{
    const float* x   = (const float*)d_in[0];
    const float* Wk  = (const float*)d_in[1];
    const float* Wq  = (const float*)d_in[2];
    const float* Wv  = (const float*)d_in[3];
    const float* Wp  = (const float*)d_in[4];
    const float* bp  = (const float*)d_in[5];
    const float* g1  = (const float*)d_in[6];
    const float* b1  = (const float*)d_in[7];
    const float* g2  = (const float*)d_in[8];
    const float* b2  = (const float*)d_in[9];
    const float* W1  = (const float*)d_in[10];
    const float* bm1 = (const float*)d_in[11];
    const float* W2  = (const float*)d_in[12];
    const float* bm2 = (const float*)d_in[13];

    char* ws = (char*)d_ws;
    const size_t MB = 1024 * 1024;
    bf16_t* Wqkvt = (bf16_t*)(ws + 0 * MB);  // 6MB [3072][1024]: Q^T|K^T|V^T
    bf16_t* Wpt = (bf16_t*)(ws + 6 * MB);    // 2MB
    bf16_t* W1t = (bf16_t*)(ws + 8 * MB);    // 8MB  [4096][1024]
    bf16_t* W2t = (bf16_t*)(ws + 16 * MB);   // 8MB  [1024][4096]
    bf16_t* xn  = (bf16_t*)(ws + 24 * MB);   // 8MB (live until proj residual)
    bf16_t* qkv = (bf16_t*)(ws + 32 * MB);   // fused QKV out base (24MB)
    bf16_t* qb  = (bf16_t*)(ws + 32 * MB);   // 8MB [b][h][s][d], Q pre-scaled
    bf16_t* kb  = (bf16_t*)(ws + 40 * MB);   // 8MB [b][h][s][d]
    bf16_t* vtb = (bf16_t*)(ws + 48 * MB);   // 8MB [b][h][d][s]
    bf16_t* yb  = (bf16_t*)(ws + 56 * MB);   // 8MB merged attn out
    float*  hbuf= (float*) (ws + 64 * MB);   // 16MB fp32 (written after merge)
    bf16_t* po  = (bf16_t*)(ws + 64 * MB);   // 32MB attn partials (dead at proj)
    float*  pls = (float*) (ws + 96 * MB);   // 1MB  lsum partials
    bf16_t* hn  = (bf16_t*)(ws + 24 * MB);   // reuse xn slot (xn dead by then)
    bf16_t* act = (bf16_t*)(ws + 32 * MB);   // 32MB, reuses qkv region

    transpose_all6<<<12288, dim3(32, 8), 0, stream>>>(
        Wq, Wk, Wv, Wp, W1, W2, Wqkvt, Wpt, W1t, W2t);

    ln_kernel<<<NROWS, 256, 0, stream>>>(x, g1, b1, xn);

    // fused QKV projection: N=3072 -> 256^2 counted-vmcnt kernel (grid 16x12)
    gemm256<6><<<192, 512, 0, stream>>>(xn, Wqkvt, nullptr, qkv, NROWS, 3072, D_MODEL);

    attn_kernel<<<2048, 256, 0, stream>>>(qb, kb, vtb, po, pls);
    attn_merge<<<NROWS, 256, 0, stream>>>(po, pls, yb);

    // Wp proj: N=1024 (grid 32x16=512 at BN=64, RY=8)
    gemm128<1, 64><<<512, 256, 0, stream>>>(yb, Wpt, bp, xn, hbuf, NROWS, D_MODEL, D_MODEL, 8);

    ln_kernel<<<NROWS, 256, 0, stream>>>(hbuf, g2, b2, hn);

    // MLP up: N=4096 -> 256^2 counted-vmcnt kernel (grid 16x16=256)
    gemm256<2><<<256, 512, 0, stream>>>(hn, W1t, bm1, act, NROWS, D_FF, D_MODEL);
    // MLP down: N=1024, K=4096 (grid 32x16=512 at BN=64, RY=8)
    gemm128<3, 64><<<512, 256, 0, stream>>>(act, W2t, bm2, hbuf, d_out, NROWS, D_MODEL, D_FF, 8);
}

// Round 9
// 337.702 us; speedup vs baseline: 1.0960x; 1.0960x over previous
//
#include <hip/hip_runtime.h>
#include <hip/hip_bf16.h>
#include <math.h>

// Problem dims (fixed by reference)
#define BATCH   2
#define SEQ     2048
#define D_MODEL 1024
#define NHEAD   16
#define HEADD   64
#define NROWS   (BATCH * SEQ)   // 4096
#define D_FF    4096
#define TPARTS  4               // attention t-split factor
#define TSPAN   (SEQ / TPARTS)  // 512

typedef __bf16 bf16_t;
typedef __bf16 bf16x2 __attribute__((ext_vector_type(2)));
typedef __bf16 bf16x4 __attribute__((ext_vector_type(4)));
typedef __bf16 bf16x8 __attribute__((ext_vector_type(8)));
typedef float  f32x4  __attribute__((ext_vector_type(4)));

#define QSCALE 0.18033688011112042f   // 0.125 * log2(e), folded into Q

// async global->LDS, 16B per lane, dest = wave-uniform base + lane*16
__device__ __forceinline__ void gload_lds16(const void* g, void* l) {
    __builtin_amdgcn_global_load_lds(
        (const __attribute__((address_space(1))) unsigned int*)g,
        (__attribute__((address_space(3))) unsigned int*)l, 16, 0, 0);
}

// ---------------------------------------------------------------------------
// Fused weight transpose + fp32 -> bf16 for all six weights (one launch).
// ---------------------------------------------------------------------------
__global__ __launch_bounds__(256) void transpose_all6(
    const float* __restrict__ Wq, const float* __restrict__ Wk,
    const float* __restrict__ Wv, const float* __restrict__ Wp,
    const float* __restrict__ W1, const float* __restrict__ W2,
    bf16_t* __restrict__ Wqkvt, bf16_t* __restrict__ Wpt,
    bf16_t* __restrict__ W1t, bf16_t* __restrict__ W2t)
{
    __shared__ float tile[32][33];
    int bid = blockIdx.x;
    const float* W; bf16_t* Wt; int K, N, n0, k0;
    if (bid < 4096) {
        int seg = bid >> 10, t = bid & 1023;
        W  = (seg == 0) ? Wq : (seg == 1) ? Wk : (seg == 2) ? Wv : Wp;
        Wt = (seg < 3) ? (Wqkvt + (size_t)seg * 1024 * 1024) : Wpt;
        K = 1024; N = 1024;
        n0 = (t & 31) * 32; k0 = (t >> 5) * 32;
    } else if (bid < 8192) {
        int t = bid - 4096;
        W = W1; Wt = W1t; K = 1024; N = 4096;
        n0 = (t & 127) * 32; k0 = (t >> 7) * 32;
    } else {
        int t = bid - 8192;
        W = W2; Wt = W2t; K = 4096; N = 1024;
        n0 = (t & 31) * 32; k0 = (t >> 5) * 32;
    }
    int tx = threadIdx.x;   // 0..31
    int ty = threadIdx.y;   // 0..7
    #pragma unroll
    for (int i = 0; i < 32; i += 8)
        tile[ty + i][tx] = W[(size_t)(k0 + ty + i) * N + n0 + tx];
    __syncthreads();
    #pragma unroll
    for (int i = 0; i < 32; i += 8)
        Wt[(size_t)(n0 + ty + i) * K + k0 + tx] = (bf16_t)tile[tx][ty + i];
}

// ---------------------------------------------------------------------------
// LayerNorm: fp32 [rows][1024] -> bf16 [rows][1024].  One block per row.
// ---------------------------------------------------------------------------
__global__ __launch_bounds__(256) void ln_kernel(
    const float* __restrict__ x, const float* __restrict__ g,
    const float* __restrict__ b, bf16_t* __restrict__ out)
{
    int row = blockIdx.x;
    int tid = threadIdx.x;
    const float* xr = x + (size_t)row * D_MODEL;
    f32x4 v = *(const f32x4*)(xr + tid * 4);
    float s  = v[0] + v[1] + v[2] + v[3];
    float s2 = v[0]*v[0] + v[1]*v[1] + v[2]*v[2] + v[3]*v[3];
    #pragma unroll
    for (int off = 32; off; off >>= 1) {
        s  += __shfl_down(s, off);
        s2 += __shfl_down(s2, off);
    }
    __shared__ float ps[4], ps2[4];
    int w = tid >> 6, lane = tid & 63;
    if (lane == 0) { ps[w] = s; ps2[w] = s2; }
    __syncthreads();
    float sum  = ps[0] + ps[1] + ps[2] + ps[3];
    float sum2 = ps2[0] + ps2[1] + ps2[2] + ps2[3];
    float mu  = sum * (1.0f / D_MODEL);
    float var = sum2 * (1.0f / D_MODEL) - mu * mu;
    float rs  = rsqrtf(var + 1e-5f);
    #pragma unroll
    for (int j = 0; j < 4; ++j) {
        int c = tid * 4 + j;
        out[(size_t)row * D_MODEL + c] = (bf16_t)((v[j] - mu) * rs * g[c] + b[c]);
    }
}

// ---------------------------------------------------------------------------
// 256x256 GEMM, 8-wave, MINIMAL-SYNC loop (R18):
// R8's counted-vmcnt phase schedule regressed (343.6->370): per-phase
// vmcnt+barrier coupling cost more than the drain it removed.  R7 analysis:
// its vmcnt(0) sits a full K-tile (~1000+cy) after issue -> drain is near
// free; the real cost was 9 barriers/K-tile (8-wave convergence each).
// Those per-phase barriers are NOT needed for correctness: stages target
// buf^1 whose prior readers completed before the iteration-top barrier;
// reads of cur are covered by the top vmcnt(0)+barrier.  So: ONE
// vmcnt(0)+s_barrier per K-tile, zero intra-tile barriers, no manual
// lgkmcnt (compiler emits fine-grained counts, m97), no setprio (no
// phase-split left to arbitrate, m190).  Quadrant code structure kept to
// cap VGPR (af[2][2] live per half; bfr[4][2] per tile).
// Chunk-XOR swizzle (rule #21): LDS[R][c] holds global chunk c^(R&7);
// staged via inverse-swz global source, read with same XOR (conflicts 0).
// EPI 2 epilogue: + bias -> GELU (tanh form, exp2+rcp) -> bf16.
// ---------------------------------------------------------------------------
__global__ __launch_bounds__(512) void gemm256_gelu(
    const bf16_t* __restrict__ A, const bf16_t* __restrict__ Bt,
    const float* __restrict__ bias, bf16_t* __restrict__ out,
    int M, int N, int K)
{
    __shared__ bf16_t As[2][256 * 64];   // [buf][row][k]
    __shared__ bf16_t Bs[2][256 * 64];
    int tid = threadIdx.x;               // 0..511
    int bid = blockIdx.x;
    int m0 = (bid & 15) * 256;           // GX = M/256 = 16
    int n0 = (bid >> 4) * 256;
    int w = tid >> 6, lane = tid & 63, quad = lane >> 4, l15 = lane & 15;
    int wm = (w >> 2) * 128;             // 0 or 128
    int wn = (w & 3) * 64;               // 0,64,128,192
    int rxs = l15 & 7;

    // staging: 512 threads, srow 0..63, chunk (tid&7); covers 64 rows/round
    int srow = tid >> 3;
    int sxor = (((tid & 7) ^ (srow & 7)) << 3);
    const bf16_t* Ap = A  + (size_t)(m0 + srow) * K + sxor;
    const bf16_t* Bp = Bt + (size_t)(n0 + srow) * K + sxor;

    f32x4 acc[8][4] = {};

    int nt = K >> 6;
    // prologue: K-tile 0 -> buf 0 (A+B, 2 halves x 2 rounds each)
    {
        bf16_t* AsW = &As[0][w * 512];
        bf16_t* BsW = &Bs[0][w * 512];
        #pragma unroll
        for (int h = 0; h < 2; ++h)
            #pragma unroll
            for (int p = 0; p < 2; ++p) {
                gload_lds16(Ap + (size_t)(h * 128 + p * 64) * K, AsW + h * 8192 + p * 4096);
                gload_lds16(Bp + (size_t)(h * 128 + p * 64) * K, BsW + h * 8192 + p * 4096);
            }
    }

    for (int t = 0; t < nt; ++t) {
        int cur = t & 1;
        const bf16_t* Asc = &As[cur][0];
        const bf16_t* Bsc = &Bs[cur][0];
        bf16_t* AsN = &As[cur ^ 1][w * 512];
        bf16_t* BsN = &Bs[cur ^ 1][w * 512];
        bool pf = (t + 1 < nt);
        int k1 = (t + 1) << 6;
        // K-tile top: my stages for buf cur landed (issued a full tile ago);
        // barrier publishes all waves' pieces AND proves all reads of buf^1
        // are done (each wave read it last iteration before arriving here).
        asm volatile("s_waitcnt vmcnt(0)" ::: "memory");
        __builtin_amdgcn_s_barrier();
        __builtin_amdgcn_sched_barrier(0);

        bf16x8 bfr[4][2];
        #pragma unroll
        for (int q = 0; q < 4; ++q) {
            bf16x8 af[2][2];
            #pragma unroll
            for (int ii = 0; ii < 2; ++ii)
                #pragma unroll
                for (int kk = 0; kk < 2; ++kk)
                    af[ii][kk] = *(const bf16x8*)&Asc[(wm + (2 * q + ii) * 16 + l15) * 64
                                                      + (((kk * 4 + quad) ^ rxs) << 3)];
            if (q == 0) {
                #pragma unroll
                for (int j = 0; j < 4; ++j)
                    #pragma unroll
                    for (int kk = 0; kk < 2; ++kk)
                        bfr[j][kk] = *(const bf16x8*)&Bsc[(wn + j * 16 + l15) * 64
                                                          + (((kk * 4 + quad) ^ rxs) << 3)];
            }
            if (q == 0 && pf) {
                #pragma unroll
                for (int h = 0; h < 2; ++h)
                    #pragma unroll
                    for (int p = 0; p < 2; ++p)
                        gload_lds16(Ap + (size_t)(h * 128 + p * 64) * K + k1,
                                    AsN + h * 8192 + p * 4096);
            }
            if (q == 1 && pf) {
                #pragma unroll
                for (int h = 0; h < 2; ++h)
                    #pragma unroll
                    for (int p = 0; p < 2; ++p)
                        gload_lds16(Bp + (size_t)(h * 128 + p * 64) * K + k1,
                                    BsN + h * 8192 + p * 4096);
            }
            // no intra-tile barriers / manual lgkmcnt: compiler tracks the
            // ds_read -> MFMA deps with fine-grained counts and is free to
            // overlap next-quadrant reads with this quadrant's MFMAs.
            #pragma unroll
            for (int ii = 0; ii < 2; ++ii)
                #pragma unroll
                for (int j = 0; j < 4; ++j)
                    #pragma unroll
                    for (int kk = 0; kk < 2; ++kk)
                        acc[2 * q + ii][j] = __builtin_amdgcn_mfma_f32_16x16x32_bf16(
                            af[ii][kk], bfr[j][kk], acc[2 * q + ii][j], 0, 0, 0);
        }
    }

    // epilogue: + bias -> GELU -> bf16
    #pragma unroll
    for (int i = 0; i < 8; ++i)
    #pragma unroll
    for (int j = 0; j < 4; ++j) {
        int col  = n0 + wn + j * 16 + l15;
        int row0 = m0 + wm + i * 16 + quad * 4;
        float bv = bias[col];
        #pragma unroll
        for (int r = 0; r < 4; ++r) {
            int row = row0 + r;
            float u = acc[i][j][r] + bv;
            float y = u * (0.7978845608028654f + 0.03567740814f * u * u);
            float e = __builtin_amdgcn_exp2f(2.8853900817779268f * y);
            float r8 = __builtin_amdgcn_rcpf(e + 1.0f);
            out[(size_t)row * N + col] = (bf16_t)(u - u * r8);
        }
    }
}

// ---------------------------------------------------------------------------
// 128xBN GEMM, BK=64, counted-vmcnt pipeline (R4/R6-proven config).
// EPI 1: + bias + bf16 residual -> fp32 out;  EPI 3: + bias + fp32 residual
// -> fp32 out;  EPI 6: fused QKV scatter.
// ---------------------------------------------------------------------------
template<int EPI, int BN>
__global__ __launch_bounds__(256) void gemm128(
    const bf16_t* __restrict__ A, const bf16_t* __restrict__ Bt,
    const float* __restrict__ bias, const void* __restrict__ resid,
    void* __restrict__ out, int M, int N, int K, int RY)
{
    constexpr int JN = BN / 32;           // j-tiles per wave
    constexpr int NBUF = (BN == 64) ? 3 : 2;
    __shared__ bf16_t As[NBUF][128 * 64];   // [buf][row][k], swizzled chunks
    __shared__ bf16_t Bs[NBUF][BN * 64];
    int tid = threadIdx.x;
    // XCD supertile swizzle (bijective; grid is 1D, GX=32)
    int bid = blockIdx.x;
    int cx = bid & 3, cy = (bid >> 2) & 1, i0 = bid >> 3;
    int m0 = ((cx << 3) + (i0 & 7)) << 7;       // x * 128
    int n0 = (cy * RY + (i0 >> 3)) * BN;
    int w = tid >> 6, lane = tid & 63, quad = lane >> 4, l15 = lane & 15;
    int wm = (w & 1) * 64, wn = (w >> 1) * (BN / 2);
    int srow = tid >> 3;              // 0..31 (staging row within pass)
    int sxor = (((tid & 7) ^ (srow & 7)) << 3);

    const bf16_t* Ap = A  + (size_t)(m0 + srow) * K + sxor;
    const bf16_t* Bp = Bt + (size_t)(n0 + srow) * K + sxor;

    int rxs = l15 & 7;                // read-side xor (chunk units); row&7==l15&7

    auto stage = [&](int buf, int k0) {
        bf16_t* AsW = &As[buf][w * 512];   // wave-uniform dest (8 rows * 64)
        bf16_t* BsW = &Bs[buf][w * 512];
        #pragma unroll
        for (int p = 0; p < 4; ++p)
            gload_lds16(Ap + (size_t)p * 32 * K + k0, AsW + p * 2048);
        #pragma unroll
        for (int p = 0; p < JN; ++p)
            gload_lds16(Bp + (size_t)p * 32 * K + k0, BsW + p * 2048);
    };

    f32x4 acc[4][JN] = {};

    int nt = K >> 6;
    stage(0, 0);                           // prologue: tile 0 -> buf 0
    if (NBUF == 3 && nt > 1) stage(1, 64); // depth-2 prologue: tile 1 -> buf 1
    for (int t = 0; t < nt; ++t) {
        int cur = t % NBUF;
        if constexpr (NBUF == 3) {
            if (t + 2 < nt) {
                stage((t + 2) % NBUF, (t + 2) << 6);
                asm volatile("s_waitcnt vmcnt(12)" ::: "memory");
            } else if (t + 1 < nt) {
                asm volatile("s_waitcnt vmcnt(6)" ::: "memory");
            } else {
                asm volatile("s_waitcnt vmcnt(0)" ::: "memory");
            }
        } else {
            if (t + 1 < nt) {
                stage((t + 1) % NBUF, (t + 1) << 6);
                asm volatile("s_waitcnt vmcnt(8)" ::: "memory");
            } else {
                asm volatile("s_waitcnt vmcnt(0)" ::: "memory");
            }
        }
        __builtin_amdgcn_s_barrier();      // current tile fully in LDS
        __builtin_amdgcn_sched_barrier(0);
        #pragma unroll
        for (int kk = 0; kk < 2; ++kk) {
            bf16x8 af[4], bfr[JN];
            #pragma unroll
            for (int i = 0; i < 4; ++i)
                af[i] = *(const bf16x8*)&As[cur][(wm + i * 16 + l15) * 64
                                            + ((((kk << 2) | quad) ^ rxs) << 3)];
            #pragma unroll
            for (int j = 0; j < JN; ++j)
                bfr[j] = *(const bf16x8*)&Bs[cur][(wn + j * 16 + l15) * 64
                                            + ((((kk << 2) | quad) ^ rxs) << 3)];
            #pragma unroll
            for (int i = 0; i < 4; ++i)
                #pragma unroll
                for (int j = 0; j < JN; ++j)
                    acc[i][j] = __builtin_amdgcn_mfma_f32_16x16x32_bf16(af[i], bfr[j], acc[i][j], 0, 0, 0);
        }
        __builtin_amdgcn_sched_barrier(0);
        asm volatile("s_waitcnt lgkmcnt(0)" ::: "memory");  // my reads done
        __builtin_amdgcn_s_barrier();      // all readers done -> buf reusable
        __builtin_amdgcn_sched_barrier(0);
    }

    #pragma unroll
    for (int i = 0; i < 4; ++i)
    #pragma unroll
    for (int j = 0; j < JN; ++j) {
        int col  = n0 + wn + j * 16 + l15;
        int row0 = m0 + wm + i * 16 + quad * 4;
        if (EPI == 6) {
            int region = (n0 + wn + j * 16) >> 10;   // 0=Q 1=K 2=V (uniform per j-tile)
            if (region < 2) {
                #pragma unroll
                for (int r = 0; r < 4; ++r) {
                    int row = row0 + r;
                    float v = acc[i][j][r];
                    if (region == 0) v *= QSCALE;
                    int b = row >> 11, s = row & 2047, hh = (col & 1023) >> 6, d = col & 63;
                    bf16_t* dst = (bf16_t*)out + (size_t)region * 4194304;
                    dst[(((size_t)(b * NHEAD + hh)) * SEQ + s) * HEADD + d] = (bf16_t)v;
                }
            } else {
                int dg = col - 2048, hh = dg >> 6, d = dg & 63;
                int b = row0 >> 11, s0 = row0 & 2047;
                bf16x4 pv;
                #pragma unroll
                for (int r = 0; r < 4; ++r) pv[r] = (bf16_t)acc[i][j][r];
                *(bf16x4*)((bf16_t*)out + 8388608
                           + (((size_t)(b * NHEAD + hh)) * HEADD + d) * SEQ + s0) = pv;
            }
        } else {
            float bv = bias[col];
            #pragma unroll
            for (int r = 0; r < 4; ++r) {
                int row = row0 + r;
                float vacc = acc[i][j][r] + bv;
                if (EPI == 1) {
                    float res = (float)((const bf16_t*)resid)[(size_t)row * N + col];
                    ((float*)out)[(size_t)row * N + col] = vacc + res;
                } else {
                    float res = ((const float*)resid)[(size_t)row * N + col];
                    ((float*)out)[(size_t)row * N + col] = vacc + res;
                }
            }
        }
    }
}

// ---------------------------------------------------------------------------
// Attention partial kernel.  No-max softmax (Q pre-scaled; exp2 direct) is
// LINEAR in t -> TPARTS=4 t-ranges of 512; partial o (bf16) + partial l.
// ---------------------------------------------------------------------------
__global__ __launch_bounds__(256, 4) void attn_kernel(
    const bf16_t* __restrict__ q, const bf16_t* __restrict__ k,
    const bf16_t* __restrict__ vt, bf16_t* __restrict__ po,
    float* __restrict__ plsum)
{
    int gid = blockIdx.x;                 // 0..2047
    int xcd = gid & 7;                    // presumed XCD (any bijection safe)
    int loc = gid >> 3;                   // 0..255
    int bh  = xcd * 4 + (loc >> 6);       // 4 consecutive heads per XCD
    int rest = loc & 63;
    int qt   = rest >> 2;                 // q-tile 0..15
    int part = rest & 3;                  // t-part 0..3
    int tb0 = part * TSPAN, tend = tb0 + TSPAN;
    int b = bh >> 4, h = bh & 15;
    int tid = threadIdx.x, w = tid >> 6, lane = tid & 63;
    int quad = lane >> 4, l15 = lane & 15;
    int qbase = qt * 128 + w * 32;
    const bf16_t* qh = q  + (size_t)bh * SEQ * HEADD;
    const bf16_t* kh = k  + (size_t)bh * SEQ * HEADD;
    const bf16_t* vh = vt + (size_t)bh * HEADD * SEQ;   // [d][t]

    bf16x8 qa[2][2];
    #pragma unroll
    for (int m = 0; m < 2; ++m)
        #pragma unroll
        for (int hf = 0; hf < 2; ++hf)
            qa[m][hf] = *(const bf16x8*)(qh + (size_t)(qbase + m * 16 + l15) * HEADD + hf * 32 + quad * 8);

    bf16x8 ones;
    #pragma unroll
    for (int j = 0; j < 8; ++j) ones[j] = (bf16_t)1.0f;

    __shared__ alignas(16) bf16_t Ks[32 * 72];     // [t][d], rows padded to 72
    __shared__ alignas(16) bf16_t Vs[64 * 40];     // [d][t], rows padded to 40
    __shared__ alignas(16) bf16_t Pl[4][32][40];   // per-wave P (32q x 32t)

    // staging indices: K tile is 4KB contiguous; V tile is 64 rows x 64B
    int ksrow = tid >> 3, kscol = (tid & 7) * 8;   // t-row, d-chunk
    int vsrow = tid >> 2, vscol = (tid & 3) * 8;   // d-row, t-chunk
    const bf16_t* kg = kh + (size_t)ksrow * HEADD + kscol;
    const bf16_t* vg = vh + (size_t)vsrow * SEQ + vscol;

    f32x4 o[2][4] = {};
    f32x4 ls[2] = {};

    for (int t0 = tb0; t0 < tend; t0 += 32) {
        bf16x8 kreg = *(const bf16x8*)(kg + (size_t)t0 * HEADD);
        bf16x8 vreg = *(const bf16x8*)(vg + t0);
        __syncthreads();                           // prev-iter readers done
        *(bf16x8*)&Ks[ksrow * 72 + kscol] = kreg;
        *(bf16x8*)&Vs[vsrow * 40 + vscol] = vreg;
        __syncthreads();                           // tiles visible

        bf16x8 kb[2][2], vf[4];
        #pragma unroll
        for (int jt = 0; jt < 2; ++jt)
            #pragma unroll
            for (int hf = 0; hf < 2; ++hf)
                kb[jt][hf] = *(const bf16x8*)&Ks[(2 * l15 + jt) * 72 + hf * 32 + quad * 8];
        #pragma unroll
        for (int dn = 0; dn < 4; ++dn)
            vf[dn] = *(const bf16x8*)&Vs[(dn * 16 + l15) * 40 + quad * 8];

        #pragma unroll
        for (int m = 0; m < 2; ++m) {
            f32x4 sc[2];
            #pragma unroll
            for (int jt = 0; jt < 2; ++jt) {
                f32x4 z = {};
                z = __builtin_amdgcn_mfma_f32_16x16x32_bf16(qa[m][0], kb[jt][0], z, 0, 0, 0);
                z = __builtin_amdgcn_mfma_f32_16x16x32_bf16(qa[m][1], kb[jt][1], z, 0, 0, 0);
                sc[jt] = z;
            }
            int qm = qbase + m * 16;
            bool dg = (t0 < qm + 16) && (t0 + 32 > qm);  // wave-uniform
            #pragma unroll
            for (int r = 0; r < 4; ++r) {
                int qrow = qm + quad * 4 + r;
                float p0 = __builtin_amdgcn_exp2f(sc[0][r]);
                float p1 = __builtin_amdgcn_exp2f(sc[1][r]);
                if (dg) {
                    int tg = t0 + 2 * l15;
                    if (tg == qrow)     p0 = 0.0f;
                    if (tg + 1 == qrow) p1 = 0.0f;
                }
                bf16x2 pp = { (bf16_t)p0, (bf16_t)p1 };
                *(bf16x2*)&Pl[w][m * 16 + quad * 4 + r][2 * l15] = pp;
            }
        }
        #pragma unroll
        for (int m = 0; m < 2; ++m) {
            bf16x8 pf = *(const bf16x8*)&Pl[w][m * 16 + l15][quad * 8];
            ls[m] = __builtin_amdgcn_mfma_f32_16x16x32_bf16(pf, ones, ls[m], 0, 0, 0);
            #pragma unroll
            for (int dn = 0; dn < 4; ++dn)
                o[m][dn] = __builtin_amdgcn_mfma_f32_16x16x32_bf16(pf, vf[dn], o[m][dn], 0, 0, 0);
        }
    }

    // partial o (bf16, undivided) and partial l (fp32; every lane holds full sum)
    #pragma unroll
    for (int m = 0; m < 2; ++m)
        #pragma unroll
        for (int dn = 0; dn < 4; ++dn)
            #pragma unroll
            for (int r = 0; r < 4; ++r) {
                int qrow = qbase + m * 16 + quad * 4 + r;
                po[(((size_t)part * NROWS) + b * SEQ + qrow) * D_MODEL
                   + h * HEADD + dn * 16 + l15] = (bf16_t)o[m][dn][r];
            }
    if (l15 == 0) {
        #pragma unroll
        for (int m = 0; m < 2; ++m)
            #pragma unroll
            for (int r = 0; r < 4; ++r) {
                int qrow = qbase + m * 16 + quad * 4 + r;
                plsum[((size_t)part * 32 + bh) * SEQ + qrow] = ls[m][r];
            }
    }
}

// ---------------------------------------------------------------------------
// Merge attention partials: y = (sum_p o_p) / (sum_p l_p), bf16 out.
// ---------------------------------------------------------------------------
__global__ __launch_bounds__(256) void attn_merge(
    const bf16_t* __restrict__ po, const float* __restrict__ plsum,
    bf16_t* __restrict__ y)
{
    int row = blockIdx.x;
    int tid = threadIdx.x;
    int c = tid * 4;
    int b = row >> 11, s = row & 2047;
    int bh = b * NHEAD + (c >> 6);
    float l = 0.0f;
    f32x4 ov = {};
    #pragma unroll
    for (int p = 0; p < TPARTS; ++p) {
        l += plsum[((size_t)p * 32 + bh) * SEQ + s];
        bf16x4 t = *(const bf16x4*)&po[((size_t)p * NROWS + row) * D_MODEL + c];
        #pragma unroll
        for (int j = 0; j < 4; ++j) ov[j] += (float)t[j];
    }
    float rl = 1.0f / l;
    bf16x4 out;
    #pragma unroll
    for (int j = 0; j < 4; ++j) out[j] = (bf16_t)(ov[j] * rl);
    *(bf16x4*)&y[(size_t)row * D_MODEL + c] = out;
}

// ---------------------------------------------------------------------------
extern "C" void kernel_launch(void* const* d_in, const int* in_sizes, int n_in,
                              void* d_out, int out_size, void* d_ws, size_t ws_size,
                              hipStream_t stream)
{
    const float* x   = (const float*)d_in[0];
    const float* Wk  = (const float*)d_in[1];
    const float* Wq  = (const float*)d_in[2];
    const float* Wv  = (const float*)d_in[3];
    const float* Wp  = (const float*)d_in[4];
    const float* bp  = (const float*)d_in[5];
    const float* g1  = (const float*)d_in[6];
    const float* b1  = (const float*)d_in[7];
    const float* g2  = (const float*)d_in[8];
    const float* b2  = (const float*)d_in[9];
    const float* W1  = (const float*)d_in[10];
    const float* bm1 = (const float*)d_in[11];
    const float* W2  = (const float*)d_in[12];
    const float* bm2 = (const float*)d_in[13];

    char* ws = (char*)d_ws;
    const size_t MB = 1024 * 1024;
    bf16_t* Wqkvt = (bf16_t*)(ws + 0 * MB);  // 6MB [3072][1024]: Q^T|K^T|V^T
    bf16_t* Wpt = (bf16_t*)(ws + 6 * MB);    // 2MB
    bf16_t* W1t = (bf16_t*)(ws + 8 * MB);    // 8MB  [4096][1024]
    bf16_t* W2t = (bf16_t*)(ws + 16 * MB);   // 8MB  [1024][4096]
    bf16_t* xn  = (bf16_t*)(ws + 24 * MB);   // 8MB (live until proj residual)
    bf16_t* qkv = (bf16_t*)(ws + 32 * MB);   // fused QKV out base (24MB)
    bf16_t* qb  = (bf16_t*)(ws + 32 * MB);   // 8MB [b][h][s][d], Q pre-scaled
    bf16_t* kb  = (bf16_t*)(ws + 40 * MB);   // 8MB [b][h][s][d]
    bf16_t* vtb = (bf16_t*)(ws + 48 * MB);   // 8MB [b][h][d][s]
    bf16_t* yb  = (bf16_t*)(ws + 56 * MB);   // 8MB merged attn out
    float*  hbuf= (float*) (ws + 64 * MB);   // 16MB fp32 (written after merge)
    bf16_t* po  = (bf16_t*)(ws + 64 * MB);   // 32MB attn partials (dead at proj)
    float*  pls = (float*) (ws + 96 * MB);   // 1MB  lsum partials
    bf16_t* hn  = (bf16_t*)(ws + 24 * MB);   // reuse xn slot (xn dead by then)
    bf16_t* act = (bf16_t*)(ws + 32 * MB);   // 32MB, reuses qkv region

    transpose_all6<<<12288, dim3(32, 8), 0, stream>>>(
        Wq, Wk, Wv, Wp, W1, W2, Wqkvt, Wpt, W1t, W2t);

    ln_kernel<<<NROWS, 256, 0, stream>>>(x, g1, b1, xn);

    // fused QKV projection: N=3072 (grid 32x24=768, RY=12)
    gemm128<6, 128><<<768, 256, 0, stream>>>(xn, Wqkvt, nullptr, nullptr, qkv, NROWS, 3072, D_MODEL, 12);

    attn_kernel<<<2048, 256, 0, stream>>>(qb, kb, vtb, po, pls);
    attn_merge<<<NROWS, 256, 0, stream>>>(po, pls, yb);

    // Wp proj: N=1024 (grid 32x16=512 at BN=64, RY=8)
    gemm128<1, 64><<<512, 256, 0, stream>>>(yb, Wpt, bp, xn, hbuf, NROWS, D_MODEL, D_MODEL, 8);

    ln_kernel<<<NROWS, 256, 0, stream>>>(hbuf, g2, b2, hn);

    // MLP up: N=4096 -> 256^2 minimal-sync kernel (grid 16x16=256)
    gemm256_gelu<<<256, 512, 0, stream>>>(hn, W1t, bm1, act, NROWS, D_FF, D_MODEL);
    // MLP down: N=1024, K=4096 (grid 32x16=512 at BN=64, RY=8)
    gemm128<3, 64><<<512, 256, 0, stream>>>(act, W2t, bm2, hbuf, d_out, NROWS, D_MODEL, D_FF, 8);
}

// Round 10
// 332.438 us; speedup vs baseline: 1.1133x; 1.0158x over previous
//
#include <hip/hip_runtime.h>
#include <hip/hip_bf16.h>
#include <math.h>

// Problem dims (fixed by reference)
#define BATCH   2
#define SEQ     2048
#define D_MODEL 1024
#define NHEAD   16
#define HEADD   64
#define NROWS   (BATCH * SEQ)   // 4096
#define D_FF    4096
#define TPARTS  4               // attention t-split factor
#define TSPAN   (SEQ / TPARTS)  // 512

typedef __bf16 bf16_t;
typedef __bf16 bf16x2 __attribute__((ext_vector_type(2)));
typedef __bf16 bf16x4 __attribute__((ext_vector_type(4)));
typedef __bf16 bf16x8 __attribute__((ext_vector_type(8)));
typedef float  f32x4  __attribute__((ext_vector_type(4)));

#define QSCALE 0.18033688011112042f   // 0.125 * log2(e), folded into Q

// async global->LDS, 16B per lane, dest = wave-uniform base + lane*16
__device__ __forceinline__ void gload_lds16(const void* g, void* l) {
    __builtin_amdgcn_global_load_lds(
        (const __attribute__((address_space(1))) unsigned int*)g,
        (__attribute__((address_space(3))) unsigned int*)l, 16, 0, 0);
}

// ---------------------------------------------------------------------------
// Fused weight transpose + fp32 -> bf16 for all six weights (one launch).
// ---------------------------------------------------------------------------
__global__ __launch_bounds__(256) void transpose_all6(
    const float* __restrict__ Wq, const float* __restrict__ Wk,
    const float* __restrict__ Wv, const float* __restrict__ Wp,
    const float* __restrict__ W1, const float* __restrict__ W2,
    bf16_t* __restrict__ Wqkvt, bf16_t* __restrict__ Wpt,
    bf16_t* __restrict__ W1t, bf16_t* __restrict__ W2t)
{
    __shared__ float tile[32][33];
    int bid = blockIdx.x;
    const float* W; bf16_t* Wt; int K, N, n0, k0;
    if (bid < 4096) {
        int seg = bid >> 10, t = bid & 1023;
        W  = (seg == 0) ? Wq : (seg == 1) ? Wk : (seg == 2) ? Wv : Wp;
        Wt = (seg < 3) ? (Wqkvt + (size_t)seg * 1024 * 1024) : Wpt;
        K = 1024; N = 1024;
        n0 = (t & 31) * 32; k0 = (t >> 5) * 32;
    } else if (bid < 8192) {
        int t = bid - 4096;
        W = W1; Wt = W1t; K = 1024; N = 4096;
        n0 = (t & 127) * 32; k0 = (t >> 7) * 32;
    } else {
        int t = bid - 8192;
        W = W2; Wt = W2t; K = 4096; N = 1024;
        n0 = (t & 31) * 32; k0 = (t >> 5) * 32;
    }
    int tx = threadIdx.x;   // 0..31
    int ty = threadIdx.y;   // 0..7
    #pragma unroll
    for (int i = 0; i < 32; i += 8)
        tile[ty + i][tx] = W[(size_t)(k0 + ty + i) * N + n0 + tx];
    __syncthreads();
    #pragma unroll
    for (int i = 0; i < 32; i += 8)
        Wt[(size_t)(n0 + ty + i) * K + k0 + tx] = (bf16_t)tile[tx][ty + i];
}

// ---------------------------------------------------------------------------
// LayerNorm: fp32 [rows][1024] -> bf16 [rows][1024].  One block per row.
// ---------------------------------------------------------------------------
__global__ __launch_bounds__(256) void ln_kernel(
    const float* __restrict__ x, const float* __restrict__ g,
    const float* __restrict__ b, bf16_t* __restrict__ out)
{
    int row = blockIdx.x;
    int tid = threadIdx.x;
    const float* xr = x + (size_t)row * D_MODEL;
    f32x4 v = *(const f32x4*)(xr + tid * 4);
    float s  = v[0] + v[1] + v[2] + v[3];
    float s2 = v[0]*v[0] + v[1]*v[1] + v[2]*v[2] + v[3]*v[3];
    #pragma unroll
    for (int off = 32; off; off >>= 1) {
        s  += __shfl_down(s, off);
        s2 += __shfl_down(s2, off);
    }
    __shared__ float ps[4], ps2[4];
    int w = tid >> 6, lane = tid & 63;
    if (lane == 0) { ps[w] = s; ps2[w] = s2; }
    __syncthreads();
    float sum  = ps[0] + ps[1] + ps[2] + ps[3];
    float sum2 = ps2[0] + ps2[1] + ps2[2] + ps2[3];
    float mu  = sum * (1.0f / D_MODEL);
    float var = sum2 * (1.0f / D_MODEL) - mu * mu;
    float rs  = rsqrtf(var + 1e-5f);
    #pragma unroll
    for (int j = 0; j < 4; ++j) {
        int c = tid * 4 + j;
        out[(size_t)row * D_MODEL + c] = (bf16_t)((v[j] - mu) * rs * g[c] + b[c]);
    }
}

// ---------------------------------------------------------------------------
// 256x256 GEMM, 8-wave, MINIMAL-SYNC loop (R9-proven; R19 adds EPI=6):
// One vmcnt(0)+s_barrier per K-tile; zero intra-tile barriers; stages into
// buf^1 issued after the top barrier (whose prior readers provably finished
// before the barrier -- each ds_read result is consumed by an MFMA, lgkmcnt
// FIFO).  Compiler schedules ds_read->MFMA with fine-grained counts.
// Chunk-XOR swizzle (rule #21): LDS[R][c] holds global chunk c^(R&7);
// staged via inverse-swz global source, read with same XOR (conflicts 0).
// EPI 2: + bias -> GELU (tanh form, exp2+rcp) -> bf16.
// EPI 6: fused QKV scatter: region 0 -> Q*QSCALE [b,h,s,d]; 1 -> K
//        [b,h,s,d]; 2 -> V^T packed [b][h][d][s]  (numerics verified R8).
// ---------------------------------------------------------------------------
template<int EPI>
__global__ __launch_bounds__(512) void gemm256(
    const bf16_t* __restrict__ A, const bf16_t* __restrict__ Bt,
    const float* __restrict__ bias, void* __restrict__ out,
    int M, int N, int K)
{
    __shared__ bf16_t As[2][256 * 64];   // [buf][row][k]
    __shared__ bf16_t Bs[2][256 * 64];
    int tid = threadIdx.x;               // 0..511
    int bid = blockIdx.x;
    int m0 = (bid & 15) * 256;           // GX = M/256 = 16
    int n0 = (bid >> 4) * 256;
    int w = tid >> 6, lane = tid & 63, quad = lane >> 4, l15 = lane & 15;
    int wm = (w >> 2) * 128;             // 0 or 128
    int wn = (w & 3) * 64;               // 0,64,128,192
    int rxs = l15 & 7;

    // staging: 512 threads, srow 0..63, chunk (tid&7); covers 64 rows/round
    int srow = tid >> 3;
    int sxor = (((tid & 7) ^ (srow & 7)) << 3);
    const bf16_t* Ap = A  + (size_t)(m0 + srow) * K + sxor;
    const bf16_t* Bp = Bt + (size_t)(n0 + srow) * K + sxor;

    f32x4 acc[8][4] = {};

    int nt = K >> 6;
    // prologue: K-tile 0 -> buf 0 (A+B, 2 halves x 2 rounds each)
    {
        bf16_t* AsW = &As[0][w * 512];
        bf16_t* BsW = &Bs[0][w * 512];
        #pragma unroll
        for (int h = 0; h < 2; ++h)
            #pragma unroll
            for (int p = 0; p < 2; ++p) {
                gload_lds16(Ap + (size_t)(h * 128 + p * 64) * K, AsW + h * 8192 + p * 4096);
                gload_lds16(Bp + (size_t)(h * 128 + p * 64) * K, BsW + h * 8192 + p * 4096);
            }
    }

    for (int t = 0; t < nt; ++t) {
        int cur = t & 1;
        const bf16_t* Asc = &As[cur][0];
        const bf16_t* Bsc = &Bs[cur][0];
        bf16_t* AsN = &As[cur ^ 1][w * 512];
        bf16_t* BsN = &Bs[cur ^ 1][w * 512];
        bool pf = (t + 1 < nt);
        int k1 = (t + 1) << 6;
        // K-tile top: my stages for buf cur landed (issued a full tile ago);
        // barrier publishes all waves' pieces AND proves all reads of buf^1
        // are done (each wave read it last iteration before arriving here).
        asm volatile("s_waitcnt vmcnt(0)" ::: "memory");
        __builtin_amdgcn_s_barrier();
        __builtin_amdgcn_sched_barrier(0);

        bf16x8 bfr[4][2];
        #pragma unroll
        for (int q = 0; q < 4; ++q) {
            bf16x8 af[2][2];
            #pragma unroll
            for (int ii = 0; ii < 2; ++ii)
                #pragma unroll
                for (int kk = 0; kk < 2; ++kk)
                    af[ii][kk] = *(const bf16x8*)&Asc[(wm + (2 * q + ii) * 16 + l15) * 64
                                                      + (((kk * 4 + quad) ^ rxs) << 3)];
            if (q == 0) {
                #pragma unroll
                for (int j = 0; j < 4; ++j)
                    #pragma unroll
                    for (int kk = 0; kk < 2; ++kk)
                        bfr[j][kk] = *(const bf16x8*)&Bsc[(wn + j * 16 + l15) * 64
                                                          + (((kk * 4 + quad) ^ rxs) << 3)];
            }
            if (q == 0 && pf) {
                #pragma unroll
                for (int h = 0; h < 2; ++h)
                    #pragma unroll
                    for (int p = 0; p < 2; ++p)
                        gload_lds16(Ap + (size_t)(h * 128 + p * 64) * K + k1,
                                    AsN + h * 8192 + p * 4096);
            }
            if (q == 1 && pf) {
                #pragma unroll
                for (int h = 0; h < 2; ++h)
                    #pragma unroll
                    for (int p = 0; p < 2; ++p)
                        gload_lds16(Bp + (size_t)(h * 128 + p * 64) * K + k1,
                                    BsN + h * 8192 + p * 4096);
            }
            // no intra-tile barriers / manual lgkmcnt (R9-proven).
            #pragma unroll
            for (int ii = 0; ii < 2; ++ii)
                #pragma unroll
                for (int j = 0; j < 4; ++j)
                    #pragma unroll
                    for (int kk = 0; kk < 2; ++kk)
                        acc[2 * q + ii][j] = __builtin_amdgcn_mfma_f32_16x16x32_bf16(
                            af[ii][kk], bfr[j][kk], acc[2 * q + ii][j], 0, 0, 0);
        }
    }

    #pragma unroll
    for (int i = 0; i < 8; ++i)
    #pragma unroll
    for (int j = 0; j < 4; ++j) {
        int col  = n0 + wn + j * 16 + l15;
        int row0 = m0 + wm + i * 16 + quad * 4;
        if (EPI == 6) {
            int region = (n0 + wn + j * 16) >> 10;   // 0=Q 1=K 2=V (uniform per j-tile)
            if (region < 2) {
                #pragma unroll
                for (int r = 0; r < 4; ++r) {
                    int row = row0 + r;
                    float v = acc[i][j][r];
                    if (region == 0) v *= QSCALE;
                    int b = row >> 11, s = row & 2047, hh = (col & 1023) >> 6, d = col & 63;
                    bf16_t* dst = (bf16_t*)out + (size_t)region * 4194304;
                    dst[(((size_t)(b * NHEAD + hh)) * SEQ + s) * HEADD + d] = (bf16_t)v;
                }
            } else {
                int dg = col - 2048, hh = dg >> 6, d = dg & 63;
                int b = row0 >> 11, s0 = row0 & 2047;
                bf16x4 pv;
                #pragma unroll
                for (int r = 0; r < 4; ++r) pv[r] = (bf16_t)acc[i][j][r];
                *(bf16x4*)((bf16_t*)out + 8388608
                           + (((size_t)(b * NHEAD + hh)) * HEADD + d) * SEQ + s0) = pv;
            }
        } else {
            float bv = bias[col];
            #pragma unroll
            for (int r = 0; r < 4; ++r) {
                int row = row0 + r;
                float u = acc[i][j][r] + bv;
                float y = u * (0.7978845608028654f + 0.03567740814f * u * u);
                float e = __builtin_amdgcn_exp2f(2.8853900817779268f * y);
                float r8 = __builtin_amdgcn_rcpf(e + 1.0f);
                ((bf16_t*)out)[(size_t)row * N + col] = (bf16_t)(u - u * r8);
            }
        }
    }
}

// ---------------------------------------------------------------------------
// 128x64 GEMM, BK=64, NBUF=3, SINGLE-BARRIER counted-vmcnt loop (R19):
// R9 proved (on gemm256) that the trailing lgkmcnt(0)+barrier is removable
// when stages are issued AFTER the top barrier: buf (t+2)%3 == (t-1)%3 was
// last read at t-1, and every wave's t-1 ds_reads completed before it passed
// t's top barrier (each read feeds an MFMA; lgkmcnt is FIFO).  So the loop
// is: counted vmcnt(6) [tile t landed, t+1 in flight] -> s_barrier ->
// sched_barrier(0) -> stage t+2 -> ds_reads+MFMAs.  Half the barriers of
// the R4 structure; depth-2 cover (~2 K-tiles) retained for HBM-latency
// staging (down-proj streams 32MB act).
// XCD supertile swizzle kept (R6: null but harmless).  Chunk-XOR swizzle
// rule #21 (conflicts 0 all session).
// EPI 1: + bias + bf16 residual -> fp32 out
// EPI 3: + bias + fp32 residual -> fp32 out (final)
// ---------------------------------------------------------------------------
template<int EPI>
__global__ __launch_bounds__(256) void gemm128(
    const bf16_t* __restrict__ A, const bf16_t* __restrict__ Bt,
    const float* __restrict__ bias, const void* __restrict__ resid,
    void* __restrict__ out, int M, int N, int K, int RY)
{
    __shared__ bf16_t As[3][128 * 64];   // [buf][row][k], swizzled chunks
    __shared__ bf16_t Bs[3][64 * 64];
    int tid = threadIdx.x;
    // XCD supertile swizzle (bijective; grid is 1D, GX=32)
    int bid = blockIdx.x;
    int cx = bid & 3, cy = (bid >> 2) & 1, i0 = bid >> 3;
    int m0 = ((cx << 3) + (i0 & 7)) << 7;       // x * 128
    int n0 = (cy * RY + (i0 >> 3)) * 64;
    int w = tid >> 6, lane = tid & 63, quad = lane >> 4, l15 = lane & 15;
    int wm = (w & 1) * 64, wn = (w >> 1) * 32;
    int srow = tid >> 3;              // 0..31 (staging row within pass)
    int sxor = (((tid & 7) ^ (srow & 7)) << 3);

    const bf16_t* Ap = A  + (size_t)(m0 + srow) * K + sxor;
    const bf16_t* Bp = Bt + (size_t)(n0 + srow) * K + sxor;

    int rxs = l15 & 7;                // read-side xor (chunk units); row&7==l15&7

    auto stage = [&](int buf, int k0) {
        bf16_t* AsW = &As[buf][w * 512];   // wave-uniform dest (8 rows * 64)
        bf16_t* BsW = &Bs[buf][w * 512];
        #pragma unroll
        for (int p = 0; p < 4; ++p)
            gload_lds16(Ap + (size_t)p * 32 * K + k0, AsW + p * 2048);
        #pragma unroll
        for (int p = 0; p < 2; ++p)
            gload_lds16(Bp + (size_t)p * 32 * K + k0, BsW + p * 2048);
    };

    f32x4 acc[4][2] = {};

    int nt = K >> 6;
    stage(0, 0);                           // prologue: tiles 0,1
    if (nt > 1) stage(1, 64);
    for (int t = 0; t < nt; ++t) {
        int cur = t % 3;
        // counted wait: oldest 6 (= tile t) landed; tile t+1 stays in flight
        if (t + 1 < nt) asm volatile("s_waitcnt vmcnt(6)" ::: "memory");
        else            asm volatile("s_waitcnt vmcnt(0)" ::: "memory");
        __builtin_amdgcn_s_barrier();      // tile t published; buf (t-1)%3 free
        __builtin_amdgcn_sched_barrier(0);
        if (t + 2 < nt) stage((t + 2) % 3, (t + 2) << 6);
        #pragma unroll
        for (int kk = 0; kk < 2; ++kk) {
            bf16x8 af[4], bfr[2];
            #pragma unroll
            for (int i = 0; i < 4; ++i)
                af[i] = *(const bf16x8*)&As[cur][(wm + i * 16 + l15) * 64
                                            + ((((kk << 2) | quad) ^ rxs) << 3)];
            #pragma unroll
            for (int j = 0; j < 2; ++j)
                bfr[j] = *(const bf16x8*)&Bs[cur][(wn + j * 16 + l15) * 64
                                            + ((((kk << 2) | quad) ^ rxs) << 3)];
            #pragma unroll
            for (int i = 0; i < 4; ++i)
                #pragma unroll
                for (int j = 0; j < 2; ++j)
                    acc[i][j] = __builtin_amdgcn_mfma_f32_16x16x32_bf16(af[i], bfr[j], acc[i][j], 0, 0, 0);
        }
        // no trailing sync: next iteration's top barrier covers reuse.
    }

    #pragma unroll
    for (int i = 0; i < 4; ++i)
    #pragma unroll
    for (int j = 0; j < 2; ++j) {
        int col  = n0 + wn + j * 16 + l15;
        int row0 = m0 + wm + i * 16 + quad * 4;
        float bv = bias[col];
        #pragma unroll
        for (int r = 0; r < 4; ++r) {
            int row = row0 + r;
            float vacc = acc[i][j][r] + bv;
            if (EPI == 1) {
                float res = (float)((const bf16_t*)resid)[(size_t)row * N + col];
                ((float*)out)[(size_t)row * N + col] = vacc + res;
            } else {
                float res = ((const float*)resid)[(size_t)row * N + col];
                ((float*)out)[(size_t)row * N + col] = vacc + res;
            }
        }
    }
}

// ---------------------------------------------------------------------------
// Attention partial kernel.  No-max softmax (Q pre-scaled; exp2 direct) is
// LINEAR in t -> TPARTS=4 t-ranges of 512; partial o (bf16) + partial l.
// ---------------------------------------------------------------------------
__global__ __launch_bounds__(256, 4) void attn_kernel(
    const bf16_t* __restrict__ q, const bf16_t* __restrict__ k,
    const bf16_t* __restrict__ vt, bf16_t* __restrict__ po,
    float* __restrict__ plsum)
{
    int gid = blockIdx.x;                 // 0..2047
    int xcd = gid & 7;                    // presumed XCD (any bijection safe)
    int loc = gid >> 3;                   // 0..255
    int bh  = xcd * 4 + (loc >> 6);       // 4 consecutive heads per XCD
    int rest = loc & 63;
    int qt   = rest >> 2;                 // q-tile 0..15
    int part = rest & 3;                  // t-part 0..3
    int tb0 = part * TSPAN, tend = tb0 + TSPAN;
    int b = bh >> 4, h = bh & 15;
    int tid = threadIdx.x, w = tid >> 6, lane = tid & 63;
    int quad = lane >> 4, l15 = lane & 15;
    int qbase = qt * 128 + w * 32;
    const bf16_t* qh = q  + (size_t)bh * SEQ * HEADD;
    const bf16_t* kh = k  + (size_t)bh * SEQ * HEADD;
    const bf16_t* vh = vt + (size_t)bh * HEADD * SEQ;   // [d][t]

    bf16x8 qa[2][2];
    #pragma unroll
    for (int m = 0; m < 2; ++m)
        #pragma unroll
        for (int hf = 0; hf < 2; ++hf)
            qa[m][hf] = *(const bf16x8*)(qh + (size_t)(qbase + m * 16 + l15) * HEADD + hf * 32 + quad * 8);

    bf16x8 ones;
    #pragma unroll
    for (int j = 0; j < 8; ++j) ones[j] = (bf16_t)1.0f;

    __shared__ alignas(16) bf16_t Ks[32 * 72];     // [t][d], rows padded to 72
    __shared__ alignas(16) bf16_t Vs[64 * 40];     // [d][t], rows padded to 40
    __shared__ alignas(16) bf16_t Pl[4][32][40];   // per-wave P (32q x 32t)

    // staging indices: K tile is 4KB contiguous; V tile is 64 rows x 64B
    int ksrow = tid >> 3, kscol = (tid & 7) * 8;   // t-row, d-chunk
    int vsrow = tid >> 2, vscol = (tid & 3) * 8;   // d-row, t-chunk
    const bf16_t* kg = kh + (size_t)ksrow * HEADD + kscol;
    const bf16_t* vg = vh + (size_t)vsrow * SEQ + vscol;

    f32x4 o[2][4] = {};
    f32x4 ls[2] = {};

    for (int t0 = tb0; t0 < tend; t0 += 32) {
        bf16x8 kreg = *(const bf16x8*)(kg + (size_t)t0 * HEADD);
        bf16x8 vreg = *(const bf16x8*)(vg + t0);
        __syncthreads();                           // prev-iter readers done
        *(bf16x8*)&Ks[ksrow * 72 + kscol] = kreg;
        *(bf16x8*)&Vs[vsrow * 40 + vscol] = vreg;
        __syncthreads();                           // tiles visible

        bf16x8 kb[2][2], vf[4];
        #pragma unroll
        for (int jt = 0; jt < 2; ++jt)
            #pragma unroll
            for (int hf = 0; hf < 2; ++hf)
                kb[jt][hf] = *(const bf16x8*)&Ks[(2 * l15 + jt) * 72 + hf * 32 + quad * 8];
        #pragma unroll
        for (int dn = 0; dn < 4; ++dn)
            vf[dn] = *(const bf16x8*)&Vs[(dn * 16 + l15) * 40 + quad * 8];

        #pragma unroll
        for (int m = 0; m < 2; ++m) {
            f32x4 sc[2];
            #pragma unroll
            for (int jt = 0; jt < 2; ++jt) {
                f32x4 z = {};
                z = __builtin_amdgcn_mfma_f32_16x16x32_bf16(qa[m][0], kb[jt][0], z, 0, 0, 0);
                z = __builtin_amdgcn_mfma_f32_16x16x32_bf16(qa[m][1], kb[jt][1], z, 0, 0, 0);
                sc[jt] = z;
            }
            int qm = qbase + m * 16;
            bool dg = (t0 < qm + 16) && (t0 + 32 > qm);  // wave-uniform
            #pragma unroll
            for (int r = 0; r < 4; ++r) {
                int qrow = qm + quad * 4 + r;
                float p0 = __builtin_amdgcn_exp2f(sc[0][r]);
                float p1 = __builtin_amdgcn_exp2f(sc[1][r]);
                if (dg) {
                    int tg = t0 + 2 * l15;
                    if (tg == qrow)     p0 = 0.0f;
                    if (tg + 1 == qrow) p1 = 0.0f;
                }
                bf16x2 pp = { (bf16_t)p0, (bf16_t)p1 };
                *(bf16x2*)&Pl[w][m * 16 + quad * 4 + r][2 * l15] = pp;
            }
        }
        #pragma unroll
        for (int m = 0; m < 2; ++m) {
            bf16x8 pf = *(const bf16x8*)&Pl[w][m * 16 + l15][quad * 8];
            ls[m] = __builtin_amdgcn_mfma_f32_16x16x32_bf16(pf, ones, ls[m], 0, 0, 0);
            #pragma unroll
            for (int dn = 0; dn < 4; ++dn)
                o[m][dn] = __builtin_amdgcn_mfma_f32_16x16x32_bf16(pf, vf[dn], o[m][dn], 0, 0, 0);
        }
    }

    // partial o (bf16, undivided) and partial l (fp32; every lane holds full sum)
    #pragma unroll
    for (int m = 0; m < 2; ++m)
        #pragma unroll
        for (int dn = 0; dn < 4; ++dn)
            #pragma unroll
            for (int r = 0; r < 4; ++r) {
                int qrow = qbase + m * 16 + quad * 4 + r;
                po[(((size_t)part * NROWS) + b * SEQ + qrow) * D_MODEL
                   + h * HEADD + dn * 16 + l15] = (bf16_t)o[m][dn][r];
            }
    if (l15 == 0) {
        #pragma unroll
        for (int m = 0; m < 2; ++m)
            #pragma unroll
            for (int r = 0; r < 4; ++r) {
                int qrow = qbase + m * 16 + quad * 4 + r;
                plsum[((size_t)part * 32 + bh) * SEQ + qrow] = ls[m][r];
            }
    }
}

// ---------------------------------------------------------------------------
// Merge attention partials: y = (sum_p o_p) / (sum_p l_p), bf16 out.
// ---------------------------------------------------------------------------
__global__ __launch_bounds__(256) void attn_merge(
    const bf16_t* __restrict__ po, const float* __restrict__ plsum,
    bf16_t* __restrict__ y)
{
    int row = blockIdx.x;
    int tid = threadIdx.x;
    int c = tid * 4;
    int b = row >> 11, s = row & 2047;
    int bh = b * NHEAD + (c >> 6);
    float l = 0.0f;
    f32x4 ov = {};
    #pragma unroll
    for (int p = 0; p < TPARTS; ++p) {
        l += plsum[((size_t)p * 32 + bh) * SEQ + s];
        bf16x4 t = *(const bf16x4*)&po[((size_t)p * NROWS + row) * D_MODEL + c];
        #pragma unroll
        for (int j = 0; j < 4; ++j) ov[j] += (float)t[j];
    }
    float rl = 1.0f / l;
    bf16x4 out;
    #pragma unroll
    for (int j = 0; j < 4; ++j) out[j] = (bf16_t)(ov[j] * rl);
    *(bf16x4*)&y[(size_t)row * D_MODEL + c] = out;
}

// ---------------------------------------------------------------------------
extern "C" void kernel_launch(void* const* d_in, const int* in_sizes, int n_in,
                              void* d_out, int out_size, void* d_ws, size_t ws_size,
                              hipStream_t stream)
{
    const float* x   = (const float*)d_in[0];
    const float* Wk  = (const float*)d_in[1];
    const float* Wq  = (const float*)d_in[2];
    const float* Wv  = (const float*)d_in[3];
    const float* Wp  = (const float*)d_in[4];
    const float* bp  = (const float*)d_in[5];
    const float* g1  = (const float*)d_in[6];
    const float* b1  = (const float*)d_in[7];
    const float* g2  = (const float*)d_in[8];
    const float* b2  = (const float*)d_in[9];
    const float* W1  = (const float*)d_in[10];
    const float* bm1 = (const float*)d_in[11];
    const float* W2  = (const float*)d_in[12];
    const float* bm2 = (const float*)d_in[13];

    char* ws = (char*)d_ws;
    const size_t MB = 1024 * 1024;
    bf16_t* Wqkvt = (bf16_t*)(ws + 0 * MB);  // 6MB [3072][1024]: Q^T|K^T|V^T
    bf16_t* Wpt = (bf16_t*)(ws + 6 * MB);    // 2MB
    bf16_t* W1t = (bf16_t*)(ws + 8 * MB);    // 8MB  [4096][1024]
    bf16_t* W2t = (bf16_t*)(ws + 16 * MB);   // 8MB  [1024][4096]
    bf16_t* xn  = (bf16_t*)(ws + 24 * MB);   // 8MB (live until proj residual)
    bf16_t* qkv = (bf16_t*)(ws + 32 * MB);   // fused QKV out base (24MB)
    bf16_t* qb  = (bf16_t*)(ws + 32 * MB);   // 8MB [b][h][s][d], Q pre-scaled
    bf16_t* kb  = (bf16_t*)(ws + 40 * MB);   // 8MB [b][h][s][d]
    bf16_t* vtb = (bf16_t*)(ws + 48 * MB);   // 8MB [b][h][d][s]
    bf16_t* yb  = (bf16_t*)(ws + 56 * MB);   // 8MB merged attn out
    float*  hbuf= (float*) (ws + 64 * MB);   // 16MB fp32 (written after merge)
    bf16_t* po  = (bf16_t*)(ws + 64 * MB);   // 32MB attn partials (dead at proj)
    float*  pls = (float*) (ws + 96 * MB);   // 1MB  lsum partials
    bf16_t* hn  = (bf16_t*)(ws + 24 * MB);   // reuse xn slot (xn dead by then)
    bf16_t* act = (bf16_t*)(ws + 32 * MB);   // 32MB, reuses qkv region

    transpose_all6<<<12288, dim3(32, 8), 0, stream>>>(
        Wq, Wk, Wv, Wp, W1, W2, Wqkvt, Wpt, W1t, W2t);

    ln_kernel<<<NROWS, 256, 0, stream>>>(x, g1, b1, xn);

    // fused QKV projection: N=3072 -> 256^2 minimal-sync kernel (grid 16x12)
    gemm256<6><<<192, 512, 0, stream>>>(xn, Wqkvt, nullptr, qkv, NROWS, 3072, D_MODEL);

    attn_kernel<<<2048, 256, 0, stream>>>(qb, kb, vtb, po, pls);
    attn_merge<<<NROWS, 256, 0, stream>>>(po, pls, yb);

    // Wp proj: N=1024 (grid 32x16=512, RY=8), single-barrier loop
    gemm128<1><<<512, 256, 0, stream>>>(yb, Wpt, bp, xn, hbuf, NROWS, D_MODEL, D_MODEL, 8);

    ln_kernel<<<NROWS, 256, 0, stream>>>(hbuf, g2, b2, hn);

    // MLP up: N=4096 -> 256^2 minimal-sync kernel (grid 16x16=256)
    gemm256<2><<<256, 512, 0, stream>>>(hn, W1t, bm1, act, NROWS, D_FF, D_MODEL);
    // MLP down: N=1024, K=4096 (grid 32x16=512, RY=8), single-barrier loop
    gemm128<3><<<512, 256, 0, stream>>>(act, W2t, bm2, hbuf, d_out, NROWS, D_MODEL, D_FF, 8);
}

// Round 11
// 322.449 us; speedup vs baseline: 1.1478x; 1.0310x over previous
//
#include <hip/hip_runtime.h>
#include <hip/hip_bf16.h>
#include <math.h>

// Problem dims (fixed by reference)
#define BATCH   2
#define SEQ     2048
#define D_MODEL 1024
#define NHEAD   16
#define HEADD   64
#define NROWS   (BATCH * SEQ)   // 4096
#define D_FF    4096
#define TPARTS  4               // attention t-split factor
#define TSPAN   (SEQ / TPARTS)  // 512

typedef __bf16 bf16_t;
typedef __bf16 bf16x2 __attribute__((ext_vector_type(2)));
typedef __bf16 bf16x4 __attribute__((ext_vector_type(4)));
typedef __bf16 bf16x8 __attribute__((ext_vector_type(8)));
typedef float  f32x4  __attribute__((ext_vector_type(4)));

#define QSCALE 0.18033688011112042f   // 0.125 * log2(e), folded into Q

// async global->LDS, 16B per lane, dest = wave-uniform base + lane*16
__device__ __forceinline__ void gload_lds16(const void* g, void* l) {
    __builtin_amdgcn_global_load_lds(
        (const __attribute__((address_space(1))) unsigned int*)g,
        (__attribute__((address_space(3))) unsigned int*)l, 16, 0, 0);
}

// ---------------------------------------------------------------------------
// Fused weight transpose + fp32 -> bf16 for all six weights (one launch).
// ---------------------------------------------------------------------------
__global__ __launch_bounds__(256) void transpose_all6(
    const float* __restrict__ Wq, const float* __restrict__ Wk,
    const float* __restrict__ Wv, const float* __restrict__ Wp,
    const float* __restrict__ W1, const float* __restrict__ W2,
    bf16_t* __restrict__ Wqkvt, bf16_t* __restrict__ Wpt,
    bf16_t* __restrict__ W1t, bf16_t* __restrict__ W2t)
{
    __shared__ float tile[32][33];
    int bid = blockIdx.x;
    const float* W; bf16_t* Wt; int K, N, n0, k0;
    if (bid < 4096) {
        int seg = bid >> 10, t = bid & 1023;
        W  = (seg == 0) ? Wq : (seg == 1) ? Wk : (seg == 2) ? Wv : Wp;
        Wt = (seg < 3) ? (Wqkvt + (size_t)seg * 1024 * 1024) : Wpt;
        K = 1024; N = 1024;
        n0 = (t & 31) * 32; k0 = (t >> 5) * 32;
    } else if (bid < 8192) {
        int t = bid - 4096;
        W = W1; Wt = W1t; K = 1024; N = 4096;
        n0 = (t & 127) * 32; k0 = (t >> 7) * 32;
    } else {
        int t = bid - 8192;
        W = W2; Wt = W2t; K = 4096; N = 1024;
        n0 = (t & 31) * 32; k0 = (t >> 5) * 32;
    }
    int tx = threadIdx.x;   // 0..31
    int ty = threadIdx.y;   // 0..7
    #pragma unroll
    for (int i = 0; i < 32; i += 8)
        tile[ty + i][tx] = W[(size_t)(k0 + ty + i) * N + n0 + tx];
    __syncthreads();
    #pragma unroll
    for (int i = 0; i < 32; i += 8)
        Wt[(size_t)(n0 + ty + i) * K + k0 + tx] = (bf16_t)tile[tx][ty + i];
}

// ---------------------------------------------------------------------------
// LayerNorm: fp32 [rows][1024] -> bf16 [rows][1024].  One block per row.
// ---------------------------------------------------------------------------
__global__ __launch_bounds__(256) void ln_kernel(
    const float* __restrict__ x, const float* __restrict__ g,
    const float* __restrict__ b, bf16_t* __restrict__ out)
{
    int row = blockIdx.x;
    int tid = threadIdx.x;
    const float* xr = x + (size_t)row * D_MODEL;
    f32x4 v = *(const f32x4*)(xr + tid * 4);
    float s  = v[0] + v[1] + v[2] + v[3];
    float s2 = v[0]*v[0] + v[1]*v[1] + v[2]*v[2] + v[3]*v[3];
    #pragma unroll
    for (int off = 32; off; off >>= 1) {
        s  += __shfl_down(s, off);
        s2 += __shfl_down(s2, off);
    }
    __shared__ float ps[4], ps2[4];
    int w = tid >> 6, lane = tid & 63;
    if (lane == 0) { ps[w] = s; ps2[w] = s2; }
    __syncthreads();
    float sum  = ps[0] + ps[1] + ps[2] + ps[3];
    float sum2 = ps2[0] + ps2[1] + ps2[2] + ps2[3];
    float mu  = sum * (1.0f / D_MODEL);
    float var = sum2 * (1.0f / D_MODEL) - mu * mu;
    float rs  = rsqrtf(var + 1e-5f);
    #pragma unroll
    for (int j = 0; j < 4; ++j) {
        int c = tid * 4 + j;
        out[(size_t)row * D_MODEL + c] = (bf16_t)((v[j] - mu) * rs * g[c] + b[c]);
    }
}

// ---------------------------------------------------------------------------
// 256x256 GEMM, 8-wave, MINIMAL-SYNC loop (R9/R10-proven).
// One vmcnt(0)+s_barrier per K-tile; zero intra-tile barriers; stages into
// buf^1 issued after the top barrier.  Chunk-XOR swizzle (rule #21).
// EPI 2: + bias -> GELU -> bf16.   EPI 6: fused QKV scatter.
// ---------------------------------------------------------------------------
template<int EPI>
__global__ __launch_bounds__(512) void gemm256(
    const bf16_t* __restrict__ A, const bf16_t* __restrict__ Bt,
    const float* __restrict__ bias, void* __restrict__ out,
    int M, int N, int K)
{
    __shared__ bf16_t As[2][256 * 64];   // [buf][row][k]
    __shared__ bf16_t Bs[2][256 * 64];
    int tid = threadIdx.x;               // 0..511
    int bid = blockIdx.x;
    int m0 = (bid & 15) * 256;           // GX = M/256 = 16
    int n0 = (bid >> 4) * 256;
    int w = tid >> 6, lane = tid & 63, quad = lane >> 4, l15 = lane & 15;
    int wm = (w >> 2) * 128;             // 0 or 128
    int wn = (w & 3) * 64;               // 0,64,128,192
    int rxs = l15 & 7;

    // staging: 512 threads, srow 0..63, chunk (tid&7); covers 64 rows/round
    int srow = tid >> 3;
    int sxor = (((tid & 7) ^ (srow & 7)) << 3);
    const bf16_t* Ap = A  + (size_t)(m0 + srow) * K + sxor;
    const bf16_t* Bp = Bt + (size_t)(n0 + srow) * K + sxor;

    f32x4 acc[8][4] = {};

    int nt = K >> 6;
    // prologue: K-tile 0 -> buf 0 (A+B, 2 halves x 2 rounds each)
    {
        bf16_t* AsW = &As[0][w * 512];
        bf16_t* BsW = &Bs[0][w * 512];
        #pragma unroll
        for (int h = 0; h < 2; ++h)
            #pragma unroll
            for (int p = 0; p < 2; ++p) {
                gload_lds16(Ap + (size_t)(h * 128 + p * 64) * K, AsW + h * 8192 + p * 4096);
                gload_lds16(Bp + (size_t)(h * 128 + p * 64) * K, BsW + h * 8192 + p * 4096);
            }
    }

    for (int t = 0; t < nt; ++t) {
        int cur = t & 1;
        const bf16_t* Asc = &As[cur][0];
        const bf16_t* Bsc = &Bs[cur][0];
        bf16_t* AsN = &As[cur ^ 1][w * 512];
        bf16_t* BsN = &Bs[cur ^ 1][w * 512];
        bool pf = (t + 1 < nt);
        int k1 = (t + 1) << 6;
        asm volatile("s_waitcnt vmcnt(0)" ::: "memory");
        __builtin_amdgcn_s_barrier();
        __builtin_amdgcn_sched_barrier(0);

        bf16x8 bfr[4][2];
        #pragma unroll
        for (int q = 0; q < 4; ++q) {
            bf16x8 af[2][2];
            #pragma unroll
            for (int ii = 0; ii < 2; ++ii)
                #pragma unroll
                for (int kk = 0; kk < 2; ++kk)
                    af[ii][kk] = *(const bf16x8*)&Asc[(wm + (2 * q + ii) * 16 + l15) * 64
                                                      + (((kk * 4 + quad) ^ rxs) << 3)];
            if (q == 0) {
                #pragma unroll
                for (int j = 0; j < 4; ++j)
                    #pragma unroll
                    for (int kk = 0; kk < 2; ++kk)
                        bfr[j][kk] = *(const bf16x8*)&Bsc[(wn + j * 16 + l15) * 64
                                                          + (((kk * 4 + quad) ^ rxs) << 3)];
            }
            if (q == 0 && pf) {
                #pragma unroll
                for (int h = 0; h < 2; ++h)
                    #pragma unroll
                    for (int p = 0; p < 2; ++p)
                        gload_lds16(Ap + (size_t)(h * 128 + p * 64) * K + k1,
                                    AsN + h * 8192 + p * 4096);
            }
            if (q == 1 && pf) {
                #pragma unroll
                for (int h = 0; h < 2; ++h)
                    #pragma unroll
                    for (int p = 0; p < 2; ++p)
                        gload_lds16(Bp + (size_t)(h * 128 + p * 64) * K + k1,
                                    BsN + h * 8192 + p * 4096);
            }
            #pragma unroll
            for (int ii = 0; ii < 2; ++ii)
                #pragma unroll
                for (int j = 0; j < 4; ++j)
                    #pragma unroll
                    for (int kk = 0; kk < 2; ++kk)
                        acc[2 * q + ii][j] = __builtin_amdgcn_mfma_f32_16x16x32_bf16(
                            af[ii][kk], bfr[j][kk], acc[2 * q + ii][j], 0, 0, 0);
        }
    }

    #pragma unroll
    for (int i = 0; i < 8; ++i)
    #pragma unroll
    for (int j = 0; j < 4; ++j) {
        int col  = n0 + wn + j * 16 + l15;
        int row0 = m0 + wm + i * 16 + quad * 4;
        if (EPI == 6) {
            int region = (n0 + wn + j * 16) >> 10;   // 0=Q 1=K 2=V (uniform per j-tile)
            if (region < 2) {
                #pragma unroll
                for (int r = 0; r < 4; ++r) {
                    int row = row0 + r;
                    float v = acc[i][j][r];
                    if (region == 0) v *= QSCALE;
                    int b = row >> 11, s = row & 2047, hh = (col & 1023) >> 6, d = col & 63;
                    bf16_t* dst = (bf16_t*)out + (size_t)region * 4194304;
                    dst[(((size_t)(b * NHEAD + hh)) * SEQ + s) * HEADD + d] = (bf16_t)v;
                }
            } else {
                int dg = col - 2048, hh = dg >> 6, d = dg & 63;
                int b = row0 >> 11, s0 = row0 & 2047;
                bf16x4 pv;
                #pragma unroll
                for (int r = 0; r < 4; ++r) pv[r] = (bf16_t)acc[i][j][r];
                *(bf16x4*)((bf16_t*)out + 8388608
                           + (((size_t)(b * NHEAD + hh)) * HEADD + d) * SEQ + s0) = pv;
            }
        } else {
            float bv = bias[col];
            #pragma unroll
            for (int r = 0; r < 4; ++r) {
                int row = row0 + r;
                float u = acc[i][j][r] + bv;
                float y = u * (0.7978845608028654f + 0.03567740814f * u * u);
                float e = __builtin_amdgcn_exp2f(2.8853900817779268f * y);
                float r8 = __builtin_amdgcn_rcpf(e + 1.0f);
                ((bf16_t*)out)[(size_t)row * N + col] = (bf16_t)(u - u * r8);
            }
        }
    }
}

// ---------------------------------------------------------------------------
// 128x128xBK=128 GEMM, 8-wave, minimal-sync loop (R20):
// The N=1024 GEMMs were pinned in the ~550TF 128x64 family because no large
// tile fits their grid at BK=64.  This tile has IDENTICAL per-K-tile
// economics to the proven gemm256 (256 MFMA + 64KB staged, 64 FLOP/B,
// 512thr / 128KB LDS / 1 blk/CU, same one-vmcnt(0)+one-barrier loop) but
// grid = (4096/128)x(1024/128) = 256 blocks = FULL CU coverage at N=1024.
// Waves 2Mx4N: wave output 64x32 (acc[4][2]).  BK=128 -> 16 chunks/row;
// swizzle XORs low 3 chunk bits with row&7 on stage-source and read-slot
// (rule #21; 2-way bank aliasing = free).  Staging: 8 rounds (4 A + 4 B),
// tid-linear 16B DMA; A rounds issued after quadrant 0, B after quadrant 1.
// EPI 1: + bias + bf16 residual -> fp32.  EPI 3: + bias + fp32 resid -> fp32.
// ---------------------------------------------------------------------------
template<int EPI>
__global__ __launch_bounds__(512) void gemm128sq(
    const bf16_t* __restrict__ A, const bf16_t* __restrict__ Bt,
    const float* __restrict__ bias, const void* __restrict__ resid,
    void* __restrict__ out, int M, int N, int K)
{
    __shared__ bf16_t As[2][128 * 128];   // [buf][row][k] 32KB each
    __shared__ bf16_t Bs[2][128 * 128];
    int tid = threadIdx.x;                // 0..511
    int bid = blockIdx.x;
    int m0 = (bid & 31) * 128;            // GX = 32
    int n0 = (bid >> 5) * 128;
    int w = tid >> 6, lane = tid & 63, quad = lane >> 4, l15 = lane & 15;
    int wm = (w >> 2) * 64;               // 0 or 64
    int wn = (w & 3) * 32;                // 0,32,64,96
    int rxs = l15 & 7;

    // staging: round p = rows p*32..p*32+31; srow = tid>>4, schunk = tid&15
    int srow = tid >> 4;
    int sxor = (((tid & 15) ^ (srow & 7)) << 3);
    const bf16_t* Ap = A  + (size_t)(m0 + srow) * K + sxor;
    const bf16_t* Bp = Bt + (size_t)(n0 + srow) * K + sxor;

    f32x4 acc[4][2] = {};
    int nt = K >> 7;

    // prologue: tile 0 -> buf 0 (A rounds 0-3, B rounds 0-3)
    {
        bf16_t* AsW = &As[0][w * 512];
        bf16_t* BsW = &Bs[0][w * 512];
        #pragma unroll
        for (int p = 0; p < 4; ++p) {
            gload_lds16(Ap + (size_t)p * 32 * K, AsW + p * 4096);
            gload_lds16(Bp + (size_t)p * 32 * K, BsW + p * 4096);
        }
    }

    for (int t = 0; t < nt; ++t) {
        int cur = t & 1;
        const bf16_t* Asc = &As[cur][0];
        const bf16_t* Bsc = &Bs[cur][0];
        bf16_t* AsN = &As[cur ^ 1][w * 512];
        bf16_t* BsN = &Bs[cur ^ 1][w * 512];
        bool pf = (t + 1 < nt);
        int k1 = (t + 1) << 7;
        // K-tile top: tile t landed (issued ~3/4 tile ago); publish; buf^1's
        // prior readers finished before this barrier (reads feed MFMAs).
        asm volatile("s_waitcnt vmcnt(0)" ::: "memory");
        __builtin_amdgcn_s_barrier();
        __builtin_amdgcn_sched_barrier(0);

        bf16x8 bfr[2][4];
        #pragma unroll
        for (int half = 0; half < 2; ++half) {
            bf16x8 af[2][4];
            #pragma unroll
            for (int ii = 0; ii < 2; ++ii)
                #pragma unroll
                for (int kk = 0; kk < 4; ++kk)
                    af[ii][kk] = *(const bf16x8*)&Asc[(wm + (2 * half + ii) * 16 + l15) * 128
                                                      + (((kk * 4 + quad) ^ rxs) << 3)];
            if (half == 0) {
                #pragma unroll
                for (int j = 0; j < 2; ++j)
                    #pragma unroll
                    for (int kk = 0; kk < 4; ++kk)
                        bfr[j][kk] = *(const bf16x8*)&Bsc[(wn + j * 16 + l15) * 128
                                                          + (((kk * 4 + quad) ^ rxs) << 3)];
                if (pf) {
                    #pragma unroll
                    for (int p = 0; p < 4; ++p)
                        gload_lds16(Ap + (size_t)p * 32 * K + k1, AsN + p * 4096);
                }
            } else if (pf) {
                #pragma unroll
                for (int p = 0; p < 4; ++p)
                    gload_lds16(Bp + (size_t)p * 32 * K + k1, BsN + p * 4096);
            }
            #pragma unroll
            for (int ii = 0; ii < 2; ++ii)
                #pragma unroll
                for (int j = 0; j < 2; ++j)
                    #pragma unroll
                    for (int kk = 0; kk < 4; ++kk)
                        acc[2 * half + ii][j] = __builtin_amdgcn_mfma_f32_16x16x32_bf16(
                            af[ii][kk], bfr[j][kk], acc[2 * half + ii][j], 0, 0, 0);
        }
    }

    #pragma unroll
    for (int i = 0; i < 4; ++i)
    #pragma unroll
    for (int j = 0; j < 2; ++j) {
        int col  = n0 + wn + j * 16 + l15;
        int row0 = m0 + wm + i * 16 + quad * 4;
        float bv = bias[col];
        #pragma unroll
        for (int r = 0; r < 4; ++r) {
            int row = row0 + r;
            float vacc = acc[i][j][r] + bv;
            if (EPI == 1) {
                float res = (float)((const bf16_t*)resid)[(size_t)row * N + col];
                ((float*)out)[(size_t)row * N + col] = vacc + res;
            } else {
                float res = ((const float*)resid)[(size_t)row * N + col];
                ((float*)out)[(size_t)row * N + col] = vacc + res;
            }
        }
    }
}

// ---------------------------------------------------------------------------
// Attention partial kernel.  No-max softmax (Q pre-scaled; exp2 direct) is
// LINEAR in t -> TPARTS=4 t-ranges of 512; partial o (bf16) + partial l.
// ---------------------------------------------------------------------------
__global__ __launch_bounds__(256, 4) void attn_kernel(
    const bf16_t* __restrict__ q, const bf16_t* __restrict__ k,
    const bf16_t* __restrict__ vt, bf16_t* __restrict__ po,
    float* __restrict__ plsum)
{
    int gid = blockIdx.x;                 // 0..2047
    int xcd = gid & 7;                    // presumed XCD (any bijection safe)
    int loc = gid >> 3;                   // 0..255
    int bh  = xcd * 4 + (loc >> 6);       // 4 consecutive heads per XCD
    int rest = loc & 63;
    int qt   = rest >> 2;                 // q-tile 0..15
    int part = rest & 3;                  // t-part 0..3
    int tb0 = part * TSPAN, tend = tb0 + TSPAN;
    int b = bh >> 4, h = bh & 15;
    int tid = threadIdx.x, w = tid >> 6, lane = tid & 63;
    int quad = lane >> 4, l15 = lane & 15;
    int qbase = qt * 128 + w * 32;
    const bf16_t* qh = q  + (size_t)bh * SEQ * HEADD;
    const bf16_t* kh = k  + (size_t)bh * SEQ * HEADD;
    const bf16_t* vh = vt + (size_t)bh * HEADD * SEQ;   // [d][t]

    bf16x8 qa[2][2];
    #pragma unroll
    for (int m = 0; m < 2; ++m)
        #pragma unroll
        for (int hf = 0; hf < 2; ++hf)
            qa[m][hf] = *(const bf16x8*)(qh + (size_t)(qbase + m * 16 + l15) * HEADD + hf * 32 + quad * 8);

    bf16x8 ones;
    #pragma unroll
    for (int j = 0; j < 8; ++j) ones[j] = (bf16_t)1.0f;

    __shared__ alignas(16) bf16_t Ks[32 * 72];     // [t][d], rows padded to 72
    __shared__ alignas(16) bf16_t Vs[64 * 40];     // [d][t], rows padded to 40
    __shared__ alignas(16) bf16_t Pl[4][32][40];   // per-wave P (32q x 32t)

    // staging indices: K tile is 4KB contiguous; V tile is 64 rows x 64B
    int ksrow = tid >> 3, kscol = (tid & 7) * 8;   // t-row, d-chunk
    int vsrow = tid >> 2, vscol = (tid & 3) * 8;   // d-row, t-chunk
    const bf16_t* kg = kh + (size_t)ksrow * HEADD + kscol;
    const bf16_t* vg = vh + (size_t)vsrow * SEQ + vscol;

    f32x4 o[2][4] = {};
    f32x4 ls[2] = {};

    for (int t0 = tb0; t0 < tend; t0 += 32) {
        bf16x8 kreg = *(const bf16x8*)(kg + (size_t)t0 * HEADD);
        bf16x8 vreg = *(const bf16x8*)(vg + t0);
        __syncthreads();                           // prev-iter readers done
        *(bf16x8*)&Ks[ksrow * 72 + kscol] = kreg;
        *(bf16x8*)&Vs[vsrow * 40 + vscol] = vreg;
        __syncthreads();                           // tiles visible

        bf16x8 kb[2][2], vf[4];
        #pragma unroll
        for (int jt = 0; jt < 2; ++jt)
            #pragma unroll
            for (int hf = 0; hf < 2; ++hf)
                kb[jt][hf] = *(const bf16x8*)&Ks[(2 * l15 + jt) * 72 + hf * 32 + quad * 8];
        #pragma unroll
        for (int dn = 0; dn < 4; ++dn)
            vf[dn] = *(const bf16x8*)&Vs[(dn * 16 + l15) * 40 + quad * 8];

        #pragma unroll
        for (int m = 0; m < 2; ++m) {
            f32x4 sc[2];
            #pragma unroll
            for (int jt = 0; jt < 2; ++jt) {
                f32x4 z = {};
                z = __builtin_amdgcn_mfma_f32_16x16x32_bf16(qa[m][0], kb[jt][0], z, 0, 0, 0);
                z = __builtin_amdgcn_mfma_f32_16x16x32_bf16(qa[m][1], kb[jt][1], z, 0, 0, 0);
                sc[jt] = z;
            }
            int qm = qbase + m * 16;
            bool dg = (t0 < qm + 16) && (t0 + 32 > qm);  // wave-uniform
            #pragma unroll
            for (int r = 0; r < 4; ++r) {
                int qrow = qm + quad * 4 + r;
                float p0 = __builtin_amdgcn_exp2f(sc[0][r]);
                float p1 = __builtin_amdgcn_exp2f(sc[1][r]);
                if (dg) {
                    int tg = t0 + 2 * l15;
                    if (tg == qrow)     p0 = 0.0f;
                    if (tg + 1 == qrow) p1 = 0.0f;
                }
                bf16x2 pp = { (bf16_t)p0, (bf16_t)p1 };
                *(bf16x2*)&Pl[w][m * 16 + quad * 4 + r][2 * l15] = pp;
            }
        }
        #pragma unroll
        for (int m = 0; m < 2; ++m) {
            bf16x8 pf = *(const bf16x8*)&Pl[w][m * 16 + l15][quad * 8];
            ls[m] = __builtin_amdgcn_mfma_f32_16x16x32_bf16(pf, ones, ls[m], 0, 0, 0);
            #pragma unroll
            for (int dn = 0; dn < 4; ++dn)
                o[m][dn] = __builtin_amdgcn_mfma_f32_16x16x32_bf16(pf, vf[dn], o[m][dn], 0, 0, 0);
        }
    }

    // partial o (bf16, undivided) and partial l (fp32; every lane holds full sum)
    #pragma unroll
    for (int m = 0; m < 2; ++m)
        #pragma unroll
        for (int dn = 0; dn < 4; ++dn)
            #pragma unroll
            for (int r = 0; r < 4; ++r) {
                int qrow = qbase + m * 16 + quad * 4 + r;
                po[(((size_t)part * NROWS) + b * SEQ + qrow) * D_MODEL
                   + h * HEADD + dn * 16 + l15] = (bf16_t)o[m][dn][r];
            }
    if (l15 == 0) {
        #pragma unroll
        for (int m = 0; m < 2; ++m)
            #pragma unroll
            for (int r = 0; r < 4; ++r) {
                int qrow = qbase + m * 16 + quad * 4 + r;
                plsum[((size_t)part * 32 + bh) * SEQ + qrow] = ls[m][r];
            }
    }
}

// ---------------------------------------------------------------------------
// Merge attention partials: y = (sum_p o_p) / (sum_p l_p), bf16 out.
// ---------------------------------------------------------------------------
__global__ __launch_bounds__(256) void attn_merge(
    const bf16_t* __restrict__ po, const float* __restrict__ plsum,
    bf16_t* __restrict__ y)
{
    int row = blockIdx.x;
    int tid = threadIdx.x;
    int c = tid * 4;
    int b = row >> 11, s = row & 2047;
    int bh = b * NHEAD + (c >> 6);
    float l = 0.0f;
    f32x4 ov = {};
    #pragma unroll
    for (int p = 0; p < TPARTS; ++p) {
        l += plsum[((size_t)p * 32 + bh) * SEQ + s];
        bf16x4 t = *(const bf16x4*)&po[((size_t)p * NROWS + row) * D_MODEL + c];
        #pragma unroll
        for (int j = 0; j < 4; ++j) ov[j] += (float)t[j];
    }
    float rl = 1.0f / l;
    bf16x4 out;
    #pragma unroll
    for (int j = 0; j < 4; ++j) out[j] = (bf16_t)(ov[j] * rl);
    *(bf16x4*)&y[(size_t)row * D_MODEL + c] = out;
}

// ---------------------------------------------------------------------------
extern "C" void kernel_launch(void* const* d_in, const int* in_sizes, int n_in,
                              void* d_out, int out_size, void* d_ws, size_t ws_size,
                              hipStream_t stream)
{
    const float* x   = (const float*)d_in[0];
    const float* Wk  = (const float*)d_in[1];
    const float* Wq  = (const float*)d_in[2];
    const float* Wv  = (const float*)d_in[3];
    const float* Wp  = (const float*)d_in[4];
    const float* bp  = (const float*)d_in[5];
    const float* g1  = (const float*)d_in[6];
    const float* b1  = (const float*)d_in[7];
    const float* g2  = (const float*)d_in[8];
    const float* b2  = (const float*)d_in[9];
    const float* W1  = (const float*)d_in[10];
    const float* bm1 = (const float*)d_in[11];
    const float* W2  = (const float*)d_in[12];
    const float* bm2 = (const float*)d_in[13];

    char* ws = (char*)d_ws;
    const size_t MB = 1024 * 1024;
    bf16_t* Wqkvt = (bf16_t*)(ws + 0 * MB);  // 6MB [3072][1024]: Q^T|K^T|V^T
    bf16_t* Wpt = (bf16_t*)(ws + 6 * MB);    // 2MB
    bf16_t* W1t = (bf16_t*)(ws + 8 * MB);    // 8MB  [4096][1024]
    bf16_t* W2t = (bf16_t*)(ws + 16 * MB);   // 8MB  [1024][4096]
    bf16_t* xn  = (bf16_t*)(ws + 24 * MB);   // 8MB (live until proj residual)
    bf16_t* qkv = (bf16_t*)(ws + 32 * MB);   // fused QKV out base (24MB)
    bf16_t* qb  = (bf16_t*)(ws + 32 * MB);   // 8MB [b][h][s][d], Q pre-scaled
    bf16_t* kb  = (bf16_t*)(ws + 40 * MB);   // 8MB [b][h][s][d]
    bf16_t* vtb = (bf16_t*)(ws + 48 * MB);   // 8MB [b][h][d][s]
    bf16_t* yb  = (bf16_t*)(ws + 56 * MB);   // 8MB merged attn out
    float*  hbuf= (float*) (ws + 64 * MB);   // 16MB fp32 (written after merge)
    bf16_t* po  = (bf16_t*)(ws + 64 * MB);   // 32MB attn partials (dead at proj)
    float*  pls = (float*) (ws + 96 * MB);   // 1MB  lsum partials
    bf16_t* hn  = (bf16_t*)(ws + 24 * MB);   // reuse xn slot (xn dead by then)
    bf16_t* act = (bf16_t*)(ws + 32 * MB);   // 32MB, reuses qkv region

    transpose_all6<<<12288, dim3(32, 8), 0, stream>>>(
        Wq, Wk, Wv, Wp, W1, W2, Wqkvt, Wpt, W1t, W2t);

    ln_kernel<<<NROWS, 256, 0, stream>>>(x, g1, b1, xn);

    // fused QKV projection: N=3072 -> 256^2 minimal-sync kernel (grid 16x12)
    gemm256<6><<<192, 512, 0, stream>>>(xn, Wqkvt, nullptr, qkv, NROWS, 3072, D_MODEL);

    attn_kernel<<<2048, 256, 0, stream>>>(qb, kb, vtb, po, pls);
    attn_merge<<<NROWS, 256, 0, stream>>>(po, pls, yb);

    // Wp proj: N=1024 -> 128^2 BK=128 8-wave kernel (grid 32x8=256, 1/CU)
    gemm128sq<1><<<256, 512, 0, stream>>>(yb, Wpt, bp, xn, hbuf, NROWS, D_MODEL, D_MODEL);

    ln_kernel<<<NROWS, 256, 0, stream>>>(hbuf, g2, b2, hn);

    // MLP up: N=4096 -> 256^2 minimal-sync kernel (grid 16x16=256)
    gemm256<2><<<256, 512, 0, stream>>>(hn, W1t, bm1, act, NROWS, D_FF, D_MODEL);
    // MLP down: N=1024, K=4096 -> 128^2 BK=128 8-wave kernel (grid 256, 1/CU)
    gemm128sq<3><<<256, 512, 0, stream>>>(act, W2t, bm2, hbuf, d_out, NROWS, D_MODEL, D_FF);
}

// Round 13
// 317.553 us; speedup vs baseline: 1.1655x; 1.0154x over previous
//
#include <hip/hip_runtime.h>
#include <hip/hip_bf16.h>
#include <math.h>

// Problem dims (fixed by reference)
#define BATCH   2
#define SEQ     2048
#define D_MODEL 1024
#define NHEAD   16
#define HEADD   64
#define NROWS   (BATCH * SEQ)   // 4096
#define D_FF    4096
#define TPARTS  4               // attention t-split factor
#define TSPAN   (SEQ / TPARTS)  // 512

typedef __bf16 bf16_t;
typedef __bf16 bf16x2 __attribute__((ext_vector_type(2)));
typedef __bf16 bf16x4 __attribute__((ext_vector_type(4)));
typedef __bf16 bf16x8 __attribute__((ext_vector_type(8)));
typedef float  f32x4  __attribute__((ext_vector_type(4)));

#define QSCALE 0.18033688011112042f   // 0.125 * log2(e), folded into Q

// async global->LDS, 16B per lane, dest = wave-uniform base + lane*16
__device__ __forceinline__ void gload_lds16(const void* g, void* l) {
    __builtin_amdgcn_global_load_lds(
        (const __attribute__((address_space(1))) unsigned int*)g,
        (__attribute__((address_space(3))) unsigned int*)l, 16, 0, 0);
}

// ---------------------------------------------------------------------------
// Fused weight transpose + fp32 -> bf16 for all six weights (one launch).
// ---------------------------------------------------------------------------
__global__ __launch_bounds__(256) void transpose_all6(
    const float* __restrict__ Wq, const float* __restrict__ Wk,
    const float* __restrict__ Wv, const float* __restrict__ Wp,
    const float* __restrict__ W1, const float* __restrict__ W2,
    bf16_t* __restrict__ Wqkvt, bf16_t* __restrict__ Wpt,
    bf16_t* __restrict__ W1t, bf16_t* __restrict__ W2t)
{
    __shared__ float tile[32][33];
    int bid = blockIdx.x;
    const float* W; bf16_t* Wt; int K, N, n0, k0;
    if (bid < 4096) {
        int seg = bid >> 10, t = bid & 1023;
        W  = (seg == 0) ? Wq : (seg == 1) ? Wk : (seg == 2) ? Wv : Wp;
        Wt = (seg < 3) ? (Wqkvt + (size_t)seg * 1024 * 1024) : Wpt;
        K = 1024; N = 1024;
        n0 = (t & 31) * 32; k0 = (t >> 5) * 32;
    } else if (bid < 8192) {
        int t = bid - 4096;
        W = W1; Wt = W1t; K = 1024; N = 4096;
        n0 = (t & 127) * 32; k0 = (t >> 7) * 32;
    } else {
        int t = bid - 8192;
        W = W2; Wt = W2t; K = 4096; N = 1024;
        n0 = (t & 31) * 32; k0 = (t >> 5) * 32;
    }
    int tx = threadIdx.x;   // 0..31
    int ty = threadIdx.y;   // 0..7
    #pragma unroll
    for (int i = 0; i < 32; i += 8)
        tile[ty + i][tx] = W[(size_t)(k0 + ty + i) * N + n0 + tx];
    __syncthreads();
    #pragma unroll
    for (int i = 0; i < 32; i += 8)
        Wt[(size_t)(n0 + ty + i) * K + k0 + tx] = (bf16_t)tile[tx][ty + i];
}

// ---------------------------------------------------------------------------
// LayerNorm: fp32 [rows][1024] -> bf16 [rows][1024].  One block per row.
// ---------------------------------------------------------------------------
__global__ __launch_bounds__(256) void ln_kernel(
    const float* __restrict__ x, const float* __restrict__ g,
    const float* __restrict__ b, bf16_t* __restrict__ out)
{
    int row = blockIdx.x;
    int tid = threadIdx.x;
    const float* xr = x + (size_t)row * D_MODEL;
    f32x4 v = *(const f32x4*)(xr + tid * 4);
    float s  = v[0] + v[1] + v[2] + v[3];
    float s2 = v[0]*v[0] + v[1]*v[1] + v[2]*v[2] + v[3]*v[3];
    #pragma unroll
    for (int off = 32; off; off >>= 1) {
        s  += __shfl_down(s, off);
        s2 += __shfl_down(s2, off);
    }
    __shared__ float ps[4], ps2[4];
    int w = tid >> 6, lane = tid & 63;
    if (lane == 0) { ps[w] = s; ps2[w] = s2; }
    __syncthreads();
    float sum  = ps[0] + ps[1] + ps[2] + ps[3];
    float sum2 = ps2[0] + ps2[1] + ps2[2] + ps2[3];
    float mu  = sum * (1.0f / D_MODEL);
    float var = sum2 * (1.0f / D_MODEL) - mu * mu;
    float rs  = rsqrtf(var + 1e-5f);
    #pragma unroll
    for (int j = 0; j < 4; ++j) {
        int c = tid * 4 + j;
        out[(size_t)row * D_MODEL + c] = (bf16_t)((v[j] - mu) * rs * g[c] + b[c]);
    }
}

// ---------------------------------------------------------------------------
// 256x256 GEMM, 8-wave, MINIMAL-SYNC loop (R9/R10-proven).
// One vmcnt(0)+s_barrier per K-tile; zero intra-tile barriers; stages into
// buf^1 issued after the top barrier.  Chunk-XOR swizzle (rule #21).
// EPI 2: + bias -> GELU -> bf16.   EPI 6: fused QKV scatter.
// ---------------------------------------------------------------------------
template<int EPI>
__global__ __launch_bounds__(512) void gemm256(
    const bf16_t* __restrict__ A, const bf16_t* __restrict__ Bt,
    const float* __restrict__ bias, void* __restrict__ out,
    int M, int N, int K)
{
    __shared__ bf16_t As[2][256 * 64];   // [buf][row][k]
    __shared__ bf16_t Bs[2][256 * 64];
    int tid = threadIdx.x;               // 0..511
    int bid = blockIdx.x;
    int m0 = (bid & 15) * 256;           // GX = M/256 = 16
    int n0 = (bid >> 4) * 256;
    int w = tid >> 6, lane = tid & 63, quad = lane >> 4, l15 = lane & 15;
    int wm = (w >> 2) * 128;             // 0 or 128
    int wn = (w & 3) * 64;               // 0,64,128,192
    int rxs = l15 & 7;

    // staging: 512 threads, srow 0..63, chunk (tid&7); covers 64 rows/round
    int srow = tid >> 3;
    int sxor = (((tid & 7) ^ (srow & 7)) << 3);
    const bf16_t* Ap = A  + (size_t)(m0 + srow) * K + sxor;
    const bf16_t* Bp = Bt + (size_t)(n0 + srow) * K + sxor;

    f32x4 acc[8][4] = {};

    int nt = K >> 6;
    // prologue: K-tile 0 -> buf 0 (A+B, 2 halves x 2 rounds each)
    {
        bf16_t* AsW = &As[0][w * 512];
        bf16_t* BsW = &Bs[0][w * 512];
        #pragma unroll
        for (int h = 0; h < 2; ++h)
            #pragma unroll
            for (int p = 0; p < 2; ++p) {
                gload_lds16(Ap + (size_t)(h * 128 + p * 64) * K, AsW + h * 8192 + p * 4096);
                gload_lds16(Bp + (size_t)(h * 128 + p * 64) * K, BsW + h * 8192 + p * 4096);
            }
    }

    for (int t = 0; t < nt; ++t) {
        int cur = t & 1;
        const bf16_t* Asc = &As[cur][0];
        const bf16_t* Bsc = &Bs[cur][0];
        bf16_t* AsN = &As[cur ^ 1][w * 512];
        bf16_t* BsN = &Bs[cur ^ 1][w * 512];
        bool pf = (t + 1 < nt);
        int k1 = (t + 1) << 6;
        asm volatile("s_waitcnt vmcnt(0)" ::: "memory");
        __builtin_amdgcn_s_barrier();
        __builtin_amdgcn_sched_barrier(0);

        bf16x8 bfr[4][2];
        #pragma unroll
        for (int q = 0; q < 4; ++q) {
            bf16x8 af[2][2];
            #pragma unroll
            for (int ii = 0; ii < 2; ++ii)
                #pragma unroll
                for (int kk = 0; kk < 2; ++kk)
                    af[ii][kk] = *(const bf16x8*)&Asc[(wm + (2 * q + ii) * 16 + l15) * 64
                                                      + (((kk * 4 + quad) ^ rxs) << 3)];
            if (q == 0) {
                #pragma unroll
                for (int j = 0; j < 4; ++j)
                    #pragma unroll
                    for (int kk = 0; kk < 2; ++kk)
                        bfr[j][kk] = *(const bf16x8*)&Bsc[(wn + j * 16 + l15) * 64
                                                          + (((kk * 4 + quad) ^ rxs) << 3)];
            }
            if (q == 0 && pf) {
                #pragma unroll
                for (int h = 0; h < 2; ++h)
                    #pragma unroll
                    for (int p = 0; p < 2; ++p)
                        gload_lds16(Ap + (size_t)(h * 128 + p * 64) * K + k1,
                                    AsN + h * 8192 + p * 4096);
            }
            if (q == 1 && pf) {
                #pragma unroll
                for (int h = 0; h < 2; ++h)
                    #pragma unroll
                    for (int p = 0; p < 2; ++p)
                        gload_lds16(Bp + (size_t)(h * 128 + p * 64) * K + k1,
                                    BsN + h * 8192 + p * 4096);
            }
            #pragma unroll
            for (int ii = 0; ii < 2; ++ii)
                #pragma unroll
                for (int j = 0; j < 4; ++j)
                    #pragma unroll
                    for (int kk = 0; kk < 2; ++kk)
                        acc[2 * q + ii][j] = __builtin_amdgcn_mfma_f32_16x16x32_bf16(
                            af[ii][kk], bfr[j][kk], acc[2 * q + ii][j], 0, 0, 0);
        }
    }

    #pragma unroll
    for (int i = 0; i < 8; ++i)
    #pragma unroll
    for (int j = 0; j < 4; ++j) {
        int col  = n0 + wn + j * 16 + l15;
        int row0 = m0 + wm + i * 16 + quad * 4;
        if (EPI == 6) {
            int region = (n0 + wn + j * 16) >> 10;   // 0=Q 1=K 2=V (uniform per j-tile)
            if (region < 2) {
                #pragma unroll
                for (int r = 0; r < 4; ++r) {
                    int row = row0 + r;
                    float v = acc[i][j][r];
                    if (region == 0) v *= QSCALE;
                    int b = row >> 11, s = row & 2047, hh = (col & 1023) >> 6, d = col & 63;
                    bf16_t* dst = (bf16_t*)out + (size_t)region * 4194304;
                    dst[(((size_t)(b * NHEAD + hh)) * SEQ + s) * HEADD + d] = (bf16_t)v;
                }
            } else {
                int dg = col - 2048, hh = dg >> 6, d = dg & 63;
                int b = row0 >> 11, s0 = row0 & 2047;
                bf16x4 pv;
                #pragma unroll
                for (int r = 0; r < 4; ++r) pv[r] = (bf16_t)acc[i][j][r];
                *(bf16x4*)((bf16_t*)out + 8388608
                           + (((size_t)(b * NHEAD + hh)) * HEADD + d) * SEQ + s0) = pv;
            }
        } else {
            float bv = bias[col];
            #pragma unroll
            for (int r = 0; r < 4; ++r) {
                int row = row0 + r;
                float u = acc[i][j][r] + bv;
                float y = u * (0.7978845608028654f + 0.03567740814f * u * u);
                float e = __builtin_amdgcn_exp2f(2.8853900817779268f * y);
                float r8 = __builtin_amdgcn_rcpf(e + 1.0f);
                ((bf16_t*)out)[(size_t)row * N + col] = (bf16_t)(u - u * r8);
            }
        }
    }
}

// ---------------------------------------------------------------------------
// 128x128xBK=128 GEMM, 8-wave, minimal-sync loop (R20/R21):
// R11 counters: the single-array [128][128] layout (256B rows) produced
// 6.29M LDS bank conflicts (= exactly 4 extra cyc per b128 wave-read),
// whereas every 128B-row layout this session measured 0.  R21: split the
// K-tile into TWO k-half sub-tiles As[buf][khalf][128*64] -- each sub-tile
// is bit-identical to the proven BK=64 geometry (128B rows, 3-bit slot
// XOR).  Staging: 4 rounds/operand of 64 rows x one k-half (srow=tid>>3,
// chunk=tid&7 -- the proven gemm256 round map), DMA-linear per wave.
// Reads index sub-tile kk>>1 with slot ((kk&1)*4+quad)^rxs.  Same 128KB
// LDS, same one-vmcnt(0)+one-barrier loop, same issue slots, same MFMAs.
// grid = 32x8 = 256 blocks = full CU coverage at N=1024.
// EPI 1: + bias + bf16 residual -> fp32.  EPI 3: + bias + fp32 resid -> fp32.
// (R22: resubmission of R12 -- GPU acquisition timeout, kernel never ran.)
// ---------------------------------------------------------------------------
template<int EPI>
__global__ __launch_bounds__(512) void gemm128sq(
    const bf16_t* __restrict__ A, const bf16_t* __restrict__ Bt,
    const float* __restrict__ bias, const void* __restrict__ resid,
    void* __restrict__ out, int M, int N, int K)
{
    __shared__ bf16_t As[2][2][128 * 64];   // [buf][khalf][row*64]
    __shared__ bf16_t Bs[2][2][128 * 64];
    int tid = threadIdx.x;                // 0..511
    int bid = blockIdx.x;
    int m0 = (bid & 31) * 128;            // GX = 32
    int n0 = (bid >> 5) * 128;
    int w = tid >> 6, lane = tid & 63, quad = lane >> 4, l15 = lane & 15;
    int wm = (w >> 2) * 64;               // 0 or 64
    int wn = (w & 3) * 32;                // 0,32,64,96
    int rxs = l15 & 7;

    // staging: 4 rounds/operand; round p: khalf = p>>1, rows (p&1)*64+srow
    int srow = tid >> 3;                  // 0..63
    int sxor = (((tid & 7) ^ (srow & 7)) << 3);
    const bf16_t* Ap = A  + (size_t)(m0 + srow) * K + sxor;
    const bf16_t* Bp = Bt + (size_t)(n0 + srow) * K + sxor;

    f32x4 acc[4][2] = {};
    int nt = K >> 7;

    // prologue: tile 0 -> buf 0 (A rounds 0-3, B rounds 0-3)
    {
        #pragma unroll
        for (int p = 0; p < 4; ++p) {
            gload_lds16(Ap + (size_t)((p & 1) * 64) * K + (p >> 1) * 64,
                        &As[0][p >> 1][(p & 1) * 4096 + w * 512]);
            gload_lds16(Bp + (size_t)((p & 1) * 64) * K + (p >> 1) * 64,
                        &Bs[0][p >> 1][(p & 1) * 4096 + w * 512]);
        }
    }

    for (int t = 0; t < nt; ++t) {
        int cur = t & 1;
        bool pf = (t + 1 < nt);
        int k1 = (t + 1) << 7;
        // K-tile top: tile t landed (issued ~3/4 tile ago); publish; buf^1's
        // prior readers finished before this barrier (reads feed MFMAs).
        asm volatile("s_waitcnt vmcnt(0)" ::: "memory");
        __builtin_amdgcn_s_barrier();
        __builtin_amdgcn_sched_barrier(0);

        bf16x8 bfr[2][4];
        #pragma unroll
        for (int half = 0; half < 2; ++half) {
            bf16x8 af[2][4];
            #pragma unroll
            for (int ii = 0; ii < 2; ++ii)
                #pragma unroll
                for (int kk = 0; kk < 4; ++kk)
                    af[ii][kk] = *(const bf16x8*)&As[cur][kk >> 1]
                        [(wm + (2 * half + ii) * 16 + l15) * 64
                         + ((((kk & 1) * 4 + quad) ^ rxs) << 3)];
            if (half == 0) {
                #pragma unroll
                for (int j = 0; j < 2; ++j)
                    #pragma unroll
                    for (int kk = 0; kk < 4; ++kk)
                        bfr[j][kk] = *(const bf16x8*)&Bs[cur][kk >> 1]
                            [(wn + j * 16 + l15) * 64
                             + ((((kk & 1) * 4 + quad) ^ rxs) << 3)];
                if (pf) {
                    #pragma unroll
                    for (int p = 0; p < 4; ++p)
                        gload_lds16(Ap + (size_t)((p & 1) * 64) * K + k1 + (p >> 1) * 64,
                                    &As[cur ^ 1][p >> 1][(p & 1) * 4096 + w * 512]);
                }
            } else if (pf) {
                #pragma unroll
                for (int p = 0; p < 4; ++p)
                    gload_lds16(Bp + (size_t)((p & 1) * 64) * K + k1 + (p >> 1) * 64,
                                &Bs[cur ^ 1][p >> 1][(p & 1) * 4096 + w * 512]);
            }
            #pragma unroll
            for (int ii = 0; ii < 2; ++ii)
                #pragma unroll
                for (int j = 0; j < 2; ++j)
                    #pragma unroll
                    for (int kk = 0; kk < 4; ++kk)
                        acc[2 * half + ii][j] = __builtin_amdgcn_mfma_f32_16x16x32_bf16(
                            af[ii][kk], bfr[j][kk], acc[2 * half + ii][j], 0, 0, 0);
        }
    }

    #pragma unroll
    for (int i = 0; i < 4; ++i)
    #pragma unroll
    for (int j = 0; j < 2; ++j) {
        int col  = n0 + wn + j * 16 + l15;
        int row0 = m0 + wm + i * 16 + quad * 4;
        float bv = bias[col];
        #pragma unroll
        for (int r = 0; r < 4; ++r) {
            int row = row0 + r;
            float vacc = acc[i][j][r] + bv;
            if (EPI == 1) {
                float res = (float)((const bf16_t*)resid)[(size_t)row * N + col];
                ((float*)out)[(size_t)row * N + col] = vacc + res;
            } else {
                float res = ((const float*)resid)[(size_t)row * N + col];
                ((float*)out)[(size_t)row * N + col] = vacc + res;
            }
        }
    }
}

// ---------------------------------------------------------------------------
// Attention partial kernel.  No-max softmax (Q pre-scaled; exp2 direct) is
// LINEAR in t -> TPARTS=4 t-ranges of 512; partial o (bf16) + partial l.
// ---------------------------------------------------------------------------
__global__ __launch_bounds__(256, 4) void attn_kernel(
    const bf16_t* __restrict__ q, const bf16_t* __restrict__ k,
    const bf16_t* __restrict__ vt, bf16_t* __restrict__ po,
    float* __restrict__ plsum)
{
    int gid = blockIdx.x;                 // 0..2047
    int xcd = gid & 7;                    // presumed XCD (any bijection safe)
    int loc = gid >> 3;                   // 0..255
    int bh  = xcd * 4 + (loc >> 6);       // 4 consecutive heads per XCD
    int rest = loc & 63;
    int qt   = rest >> 2;                 // q-tile 0..15
    int part = rest & 3;                  // t-part 0..3
    int tb0 = part * TSPAN, tend = tb0 + TSPAN;
    int b = bh >> 4, h = bh & 15;
    int tid = threadIdx.x, w = tid >> 6, lane = tid & 63;
    int quad = lane >> 4, l15 = lane & 15;
    int qbase = qt * 128 + w * 32;
    const bf16_t* qh = q  + (size_t)bh * SEQ * HEADD;
    const bf16_t* kh = k  + (size_t)bh * SEQ * HEADD;
    const bf16_t* vh = vt + (size_t)bh * HEADD * SEQ;   // [d][t]

    bf16x8 qa[2][2];
    #pragma unroll
    for (int m = 0; m < 2; ++m)
        #pragma unroll
        for (int hf = 0; hf < 2; ++hf)
            qa[m][hf] = *(const bf16x8*)(qh + (size_t)(qbase + m * 16 + l15) * HEADD + hf * 32 + quad * 8);

    bf16x8 ones;
    #pragma unroll
    for (int j = 0; j < 8; ++j) ones[j] = (bf16_t)1.0f;

    __shared__ alignas(16) bf16_t Ks[32 * 72];     // [t][d], rows padded to 72
    __shared__ alignas(16) bf16_t Vs[64 * 40];     // [d][t], rows padded to 40
    __shared__ alignas(16) bf16_t Pl[4][32][40];   // per-wave P (32q x 32t)

    // staging indices: K tile is 4KB contiguous; V tile is 64 rows x 64B
    int ksrow = tid >> 3, kscol = (tid & 7) * 8;   // t-row, d-chunk
    int vsrow = tid >> 2, vscol = (tid & 3) * 8;   // d-row, t-chunk
    const bf16_t* kg = kh + (size_t)ksrow * HEADD + kscol;
    const bf16_t* vg = vh + (size_t)vsrow * SEQ + vscol;

    f32x4 o[2][4] = {};
    f32x4 ls[2] = {};

    for (int t0 = tb0; t0 < tend; t0 += 32) {
        bf16x8 kreg = *(const bf16x8*)(kg + (size_t)t0 * HEADD);
        bf16x8 vreg = *(const bf16x8*)(vg + t0);
        __syncthreads();                           // prev-iter readers done
        *(bf16x8*)&Ks[ksrow * 72 + kscol] = kreg;
        *(bf16x8*)&Vs[vsrow * 40 + vscol] = vreg;
        __syncthreads();                           // tiles visible

        bf16x8 kb[2][2], vf[4];
        #pragma unroll
        for (int jt = 0; jt < 2; ++jt)
            #pragma unroll
            for (int hf = 0; hf < 2; ++hf)
                kb[jt][hf] = *(const bf16x8*)&Ks[(2 * l15 + jt) * 72 + hf * 32 + quad * 8];
        #pragma unroll
        for (int dn = 0; dn < 4; ++dn)
            vf[dn] = *(const bf16x8*)&Vs[(dn * 16 + l15) * 40 + quad * 8];

        #pragma unroll
        for (int m = 0; m < 2; ++m) {
            f32x4 sc[2];
            #pragma unroll
            for (int jt = 0; jt < 2; ++jt) {
                f32x4 z = {};
                z = __builtin_amdgcn_mfma_f32_16x16x32_bf16(qa[m][0], kb[jt][0], z, 0, 0, 0);
                z = __builtin_amdgcn_mfma_f32_16x16x32_bf16(qa[m][1], kb[jt][1], z, 0, 0, 0);
                sc[jt] = z;
            }
            int qm = qbase + m * 16;
            bool dg = (t0 < qm + 16) && (t0 + 32 > qm);  // wave-uniform
            #pragma unroll
            for (int r = 0; r < 4; ++r) {
                int qrow = qm + quad * 4 + r;
                float p0 = __builtin_amdgcn_exp2f(sc[0][r]);
                float p1 = __builtin_amdgcn_exp2f(sc[1][r]);
                if (dg) {
                    int tg = t0 + 2 * l15;
                    if (tg == qrow)     p0 = 0.0f;
                    if (tg + 1 == qrow) p1 = 0.0f;
                }
                bf16x2 pp = { (bf16_t)p0, (bf16_t)p1 };
                *(bf16x2*)&Pl[w][m * 16 + quad * 4 + r][2 * l15] = pp;
            }
        }
        #pragma unroll
        for (int m = 0; m < 2; ++m) {
            bf16x8 pf = *(const bf16x8*)&Pl[w][m * 16 + l15][quad * 8];
            ls[m] = __builtin_amdgcn_mfma_f32_16x16x32_bf16(pf, ones, ls[m], 0, 0, 0);
            #pragma unroll
            for (int dn = 0; dn < 4; ++dn)
                o[m][dn] = __builtin_amdgcn_mfma_f32_16x16x32_bf16(pf, vf[dn], o[m][dn], 0, 0, 0);
        }
    }

    // partial o (bf16, undivided) and partial l (fp32; every lane holds full sum)
    #pragma unroll
    for (int m = 0; m < 2; ++m)
        #pragma unroll
        for (int dn = 0; dn < 4; ++dn)
            #pragma unroll
            for (int r = 0; r < 4; ++r) {
                int qrow = qbase + m * 16 + quad * 4 + r;
                po[(((size_t)part * NROWS) + b * SEQ + qrow) * D_MODEL
                   + h * HEADD + dn * 16 + l15] = (bf16_t)o[m][dn][r];
            }
    if (l15 == 0) {
        #pragma unroll
        for (int m = 0; m < 2; ++m)
            #pragma unroll
            for (int r = 0; r < 4; ++r) {
                int qrow = qbase + m * 16 + quad * 4 + r;
                plsum[((size_t)part * 32 + bh) * SEQ + qrow] = ls[m][r];
            }
    }
}

// ---------------------------------------------------------------------------
// Merge attention partials: y = (sum_p o_p) / (sum_p l_p), bf16 out.
// ---------------------------------------------------------------------------
__global__ __launch_bounds__(256) void attn_merge(
    const bf16_t* __restrict__ po, const float* __restrict__ plsum,
    bf16_t* __restrict__ y)
{
    int row = blockIdx.x;
    int tid = threadIdx.x;
    int c = tid * 4;
    int b = row >> 11, s = row & 2047;
    int bh = b * NHEAD + (c >> 6);
    float l = 0.0f;
    f32x4 ov = {};
    #pragma unroll
    for (int p = 0; p < TPARTS; ++p) {
        l += plsum[((size_t)p * 32 + bh) * SEQ + s];
        bf16x4 t = *(const bf16x4*)&po[((size_t)p * NROWS + row) * D_MODEL + c];
        #pragma unroll
        for (int j = 0; j < 4; ++j) ov[j] += (float)t[j];
    }
    float rl = 1.0f / l;
    bf16x4 out;
    #pragma unroll
    for (int j = 0; j < 4; ++j) out[j] = (bf16_t)(ov[j] * rl);
    *(bf16x4*)&y[(size_t)row * D_MODEL + c] = out;
}

// ---------------------------------------------------------------------------
extern "C" void kernel_launch(void* const* d_in, const int* in_sizes, int n_in,
                              void* d_out, int out_size, void* d_ws, size_t ws_size,
                              hipStream_t stream)
{
    const float* x   = (const float*)d_in[0];
    const float* Wk  = (const float*)d_in[1];
    const float* Wq  = (const float*)d_in[2];
    const float* Wv  = (const float*)d_in[3];
    const float* Wp  = (const float*)d_in[4];
    const float* bp  = (const float*)d_in[5];
    const float* g1  = (const float*)d_in[6];
    const float* b1  = (const float*)d_in[7];
    const float* g2  = (const float*)d_in[8];
    const float* b2  = (const float*)d_in[9];
    const float* W1  = (const float*)d_in[10];
    const float* bm1 = (const float*)d_in[11];
    const float* W2  = (const float*)d_in[12];
    const float* bm2 = (const float*)d_in[13];

    char* ws = (char*)d_ws;
    const size_t MB = 1024 * 1024;
    bf16_t* Wqkvt = (bf16_t*)(ws + 0 * MB);  // 6MB [3072][1024]: Q^T|K^T|V^T
    bf16_t* Wpt = (bf16_t*)(ws + 6 * MB);    // 2MB
    bf16_t* W1t = (bf16_t*)(ws + 8 * MB);    // 8MB  [4096][1024]
    bf16_t* W2t = (bf16_t*)(ws + 16 * MB);   // 8MB  [1024][4096]
    bf16_t* xn  = (bf16_t*)(ws + 24 * MB);   // 8MB (live until proj residual)
    bf16_t* qkv = (bf16_t*)(ws + 32 * MB);   // fused QKV out base (24MB)
    bf16_t* qb  = (bf16_t*)(ws + 32 * MB);   // 8MB [b][h][s][d], Q pre-scaled
    bf16_t* kb  = (bf16_t*)(ws + 40 * MB);   // 8MB [b][h][s][d]
    bf16_t* vtb = (bf16_t*)(ws + 48 * MB);   // 8MB [b][h][d][s]
    bf16_t* yb  = (bf16_t*)(ws + 56 * MB);   // 8MB merged attn out
    float*  hbuf= (float*) (ws + 64 * MB);   // 16MB fp32 (written after merge)
    bf16_t* po  = (bf16_t*)(ws + 64 * MB);   // 32MB attn partials (dead at proj)
    float*  pls = (float*) (ws + 96 * MB);   // 1MB  lsum partials
    bf16_t* hn  = (bf16_t*)(ws + 24 * MB);   // reuse xn slot (xn dead by then)
    bf16_t* act = (bf16_t*)(ws + 32 * MB);   // 32MB, reuses qkv region

    transpose_all6<<<12288, dim3(32, 8), 0, stream>>>(
        Wq, Wk, Wv, Wp, W1, W2, Wqkvt, Wpt, W1t, W2t);

    ln_kernel<<<NROWS, 256, 0, stream>>>(x, g1, b1, xn);

    // fused QKV projection: N=3072 -> 256^2 minimal-sync kernel (grid 16x12)
    gemm256<6><<<192, 512, 0, stream>>>(xn, Wqkvt, nullptr, qkv, NROWS, 3072, D_MODEL);

    attn_kernel<<<2048, 256, 0, stream>>>(qb, kb, vtb, po, pls);
    attn_merge<<<NROWS, 256, 0, stream>>>(po, pls, yb);

    // Wp proj: N=1024 -> 128^2 BK=128 8-wave kernel (grid 32x8=256, 1/CU)
    gemm128sq<1><<<256, 512, 0, stream>>>(yb, Wpt, bp, xn, hbuf, NROWS, D_MODEL, D_MODEL);

    ln_kernel<<<NROWS, 256, 0, stream>>>(hbuf, g2, b2, hn);

    // MLP up: N=4096 -> 256^2 minimal-sync kernel (grid 16x16=256)
    gemm256<2><<<256, 512, 0, stream>>>(hn, W1t, bm1, act, NROWS, D_FF, D_MODEL);
    // MLP down: N=1024, K=4096 -> 128^2 BK=128 8-wave kernel (grid 256, 1/CU)
    gemm128sq<3><<<256, 512, 0, stream>>>(act, W2t, bm2, hbuf, d_out, NROWS, D_MODEL, D_FF);
}